// Round 2
// baseline (10985.833 us; speedup 1.0000x reference)
//
#include <hip/hip_runtime.h>
#include <hip/hip_bf16.h>
#include <math.h>

constexpr int Bc = 2, Lc = 2048, Dc = 1024, Hc = 16, HDc = 64, FFc = 4096;
constexpr int NT = Bc * Lc;              // 4096 tokens
constexpr size_t TD = (size_t)NT * Dc;   // 4194304 elements per [B,L,D] tensor

__device__ __forceinline__ float ldf(const float* p) { return *p; }

// ---------- block reductions (blockDim.x == 256 = 4 waves) ----------
__device__ __forceinline__ float block_sum(float v, float* red) {
  const int lane = threadIdx.x & 63, w = threadIdx.x >> 6;
  #pragma unroll
  for (int o = 32; o > 0; o >>= 1) v += __shfl_down(v, o, 64);
  __syncthreads();
  if (lane == 0) red[w] = v;
  __syncthreads();
  return red[0] + red[1] + red[2] + red[3];
}
__device__ __forceinline__ float block_max(float v, float* red) {
  const int lane = threadIdx.x & 63, w = threadIdx.x >> 6;
  #pragma unroll
  for (int o = 32; o > 0; o >>= 1) v = fmaxf(v, __shfl_down(v, o, 64));
  __syncthreads();
  if (lane == 0) red[w] = v;
  __syncthreads();
  return fmaxf(fmaxf(red[0], red[1]), fmaxf(red[2], red[3]));
}

// ---------- generic tiled fp32 GEMM: C[m,n] = sum_k A[m,k]*B[k,n] (+epilogue) ----
// TRANSA: A stored [K,M] row-major (used for proj_w^T).
constexpr int EPI_BIAS = 0, EPI_BIAS_ROW = 1, EPI_GELU = 2, EPI_ADD = 3, EPI_ADDROW0 = 4;

template<bool TRANSA, int EPI>
__global__ __launch_bounds__(256)
void gemm_kernel(const float* __restrict__ A, const float* __restrict__ B,
                 const float* __restrict__ bias, const float* __restrict__ extra,
                 float* __restrict__ C, int M, int N, int Kd,
                 long long strideB, long long strideC)
{
  __shared__ float As[16][65];   // [k][m], padded
  __shared__ float Bs[16][64];   // [k][n]
  const int tid = threadIdx.x, tx = tid & 15, ty = tid >> 4;
  const int m0 = blockIdx.y * 64, n0 = blockIdx.x * 64;
  const float* Bp = B + (long long)blockIdx.z * strideB;
  float* Cp = C + (long long)blockIdx.z * strideC;
  float acc[4][4] = {};

  for (int k0 = 0; k0 < Kd; k0 += 16) {
    #pragma unroll
    for (int i = 0; i < 4; i++) {
      const int idx = tid + i * 256;
      if (TRANSA) {
        const int kk = idx >> 6, mm = idx & 63;
        As[kk][mm] = ldf(A + (long long)(k0 + kk) * M + (m0 + mm));
      } else {
        const int r = idx >> 4, c = idx & 15;
        As[c][r] = ldf(A + (long long)(m0 + r) * Kd + (k0 + c));
      }
    }
    #pragma unroll
    for (int i = 0; i < 4; i++) {
      const int idx = tid + i * 256;
      const int kk = idx >> 6, nn = idx & 63;
      Bs[kk][nn] = ldf(Bp + (long long)(k0 + kk) * N + (n0 + nn));
    }
    __syncthreads();
    #pragma unroll
    for (int kk = 0; kk < 16; kk++) {
      const float a0 = As[kk][ty*4+0], a1 = As[kk][ty*4+1];
      const float a2 = As[kk][ty*4+2], a3 = As[kk][ty*4+3];
      const float4 b4 = *(const float4*)&Bs[kk][tx*4];
      acc[0][0] += a0*b4.x; acc[0][1] += a0*b4.y; acc[0][2] += a0*b4.z; acc[0][3] += a0*b4.w;
      acc[1][0] += a1*b4.x; acc[1][1] += a1*b4.y; acc[1][2] += a1*b4.z; acc[1][3] += a1*b4.w;
      acc[2][0] += a2*b4.x; acc[2][1] += a2*b4.y; acc[2][2] += a2*b4.z; acc[2][3] += a2*b4.w;
      acc[3][0] += a3*b4.x; acc[3][1] += a3*b4.y; acc[3][2] += a3*b4.z; acc[3][3] += a3*b4.w;
    }
    __syncthreads();
  }

  #pragma unroll
  for (int i = 0; i < 4; i++) {
    const int m = m0 + ty * 4 + i;
    const int n = n0 + tx * 4;
    float r0 = acc[i][0], r1 = acc[i][1], r2 = acc[i][2], r3 = acc[i][3];
    if constexpr (EPI == EPI_BIAS || EPI == EPI_GELU || EPI == EPI_ADD || EPI == EPI_ADDROW0) {
      r0 += ldf(bias + n + 0); r1 += ldf(bias + n + 1);
      r2 += ldf(bias + n + 2); r3 += ldf(bias + n + 3);
    }
    if constexpr (EPI == EPI_BIAS_ROW) {
      const float bm = ldf(bias + m);
      r0 += bm; r1 += bm; r2 += bm; r3 += bm;
    }
    if constexpr (EPI == EPI_GELU) {   // exact gelu: 0.5 x (1+erf(x/sqrt2))
      r0 = 0.5f * r0 * (1.0f + erff(r0 * 0.70710678118654752f));
      r1 = 0.5f * r1 * (1.0f + erff(r1 * 0.70710678118654752f));
      r2 = 0.5f * r2 * (1.0f + erff(r2 * 0.70710678118654752f));
      r3 = 0.5f * r3 * (1.0f + erff(r3 * 0.70710678118654752f));
    }
    if constexpr (EPI == EPI_ADD) {    // + extra[m,n] elementwise
      const float* e = extra + (size_t)m * N + n;
      r0 += e[0]; r1 += e[1]; r2 += e[2]; r3 += e[3];
    }
    if constexpr (EPI == EPI_ADDROW0) { // + extra[batch(m), 0, n]  (batch = m/Lc)
      const float* e = extra + (size_t)(m >> 11) * ((size_t)Lc * Dc) + n;
      r0 += e[0]; r1 += e[1]; r2 += e[2]; r3 += e[3];
    }
    *(float4*)(Cp + (size_t)m * N + n) = make_float4(r0, r1, r2, r3);
  }
}

// ---------- RoPE (reference's even/odd -> concat layout), in-place ----------
__global__ __launch_bounds__(256)
void rope_kernel(float* __restrict__ X)
{
  const int gid = blockIdx.x * 256 + threadIdx.x;  // one thread = one (token, head)
  if (gid >= NT * Hc) return;
  const int h = gid & (Hc - 1);
  const int token = gid >> 4;
  const int l = token & (Lc - 1);
  float* p = X + (size_t)token * Dc + h * HDc;
  float x[64], out[64];
  #pragma unroll
  for (int i = 0; i < 16; i++) *(float4*)&x[4*i] = *(const float4*)&p[4*i];
  const float lf = (float)l;
  #pragma unroll
  for (int i = 0; i < 32; i++) {
    const int j = (i < 16) ? (2 * i) : (2 * (i - 16));
    const float a0 = lf * powf(10000.0f, -(float)j       / 32.0f);
    const float a1 = lf * powf(10000.0f, -(float)(j + 1) / 32.0f);
    float c, s;
    if (i < 16) { c = cosf(a0); s = cosf(a1); }
    else        { c = sinf(a0); s = sinf(a1); }
    out[i]      = x[2*i] * c - x[2*i+1] * s;
    out[32 + i] = x[2*i] * s + x[2*i+1] * c;
  }
  #pragma unroll
  for (int i = 0; i < 16; i++) *(float4*)&p[4*i] = *(const float4*)&out[4*i];
}

// ---------- attention: one block per (q-row, b*H+h); full softmax row in LDS ----
__global__ __launch_bounds__(256)
void attn_kernel(const float* __restrict__ Q, const float* __restrict__ K,
                 const float* __restrict__ V, float* __restrict__ O)
{
  __shared__ float qs[HDc];
  __shared__ float sc[Lc];
  __shared__ float red4[4];
  __shared__ float pv[256];
  const int tid = threadIdx.x;
  const int qrow = blockIdx.x;
  const int bh = blockIdx.y;
  const int b = bh >> 4, h = bh & 15;
  const size_t hb = (size_t)b * Lc * Dc + (size_t)h * HDc;

  if (tid < HDc) qs[tid] = Q[hb + (size_t)qrow * Dc + tid];
  __syncthreads();

  const float slope = exp2f(-0.5f * (float)h);
  float lmax = -3.4e38f;
  for (int k = tid; k < Lc; k += 256) {
    const float4* kp = (const float4*)(K + hb + (size_t)k * Dc);
    float acc = 0.f;
    #pragma unroll
    for (int i = 0; i < 16; i++) {
      const float4 kv = kp[i];
      const float4 qq = *(const float4*)&qs[4*i];
      acc += kv.x*qq.x + kv.y*qq.y + kv.z*qq.z + kv.w*qq.w;
    }
    const float dist = (qrow > k) ? (float)(qrow - k) : 0.0f;
    const float sv = acc * 0.125f + slope * dist;   // HD^-0.5 = 1/8
    sc[k] = sv;
    lmax = fmaxf(lmax, sv);
  }
  lmax = block_max(lmax, red4);
  float lsum = 0.f;
  for (int k = tid; k < Lc; k += 256) {
    const float e = expf(sc[k] - lmax);
    sc[k] = e; lsum += e;
  }
  lsum = block_sum(lsum, red4);
  const float inv = 1.0f / lsum;

  const int d = tid & 63, p = tid >> 6;
  float acc = 0.f;
  for (int k = p; k < Lc; k += 4) acc += sc[k] * V[hb + (size_t)k * Dc + d];
  pv[tid] = acc;
  __syncthreads();
  if (tid < 64) {
    const float o = (pv[tid] + pv[64+tid] + pv[128+tid] + pv[192+tid]) * inv;
    O[hb + (size_t)qrow * Dc + tid] = o;
  }
}

// ---------- layernorm variants (one block per row, D=1024, 4 elems/thread) ----
__global__ __launch_bounds__(256)
void ln_plain_kernel(const float* __restrict__ X, const float* __restrict__ g,
                     const float* __restrict__ be, float* __restrict__ OUT)
{
  __shared__ float red4[4];
  const int row = blockIdx.x, tid = threadIdx.x;
  const size_t base = (size_t)row * Dc + tid * 4;
  const float4 xv = *(const float4*)(X + base);
  float s = xv.x + xv.y + xv.z + xv.w;
  s = block_sum(s, red4);
  const float mean = s * (1.0f / Dc);
  const float d0 = xv.x-mean, d1 = xv.y-mean, d2 = xv.z-mean, d3 = xv.w-mean;
  float ss = d0*d0 + d1*d1 + d2*d2 + d3*d3;
  ss = block_sum(ss, red4);
  const float rstd = rsqrtf(ss * (1.0f / Dc) + 1e-5f);
  const int c = tid * 4;
  float4 o;
  o.x = d0*rstd*ldf(g+c+0) + ldf(be+c+0);
  o.y = d1*rstd*ldf(g+c+1) + ldf(be+c+1);
  o.z = d2*rstd*ldf(g+c+2) + ldf(be+c+2);
  o.w = d3*rstd*ldf(g+c+3) + ldf(be+c+3);
  *(float4*)(OUT + base) = o;
}

__global__ __launch_bounds__(256)   // OUT = RES + ln(X)
void ln_resadd_kernel(const float* __restrict__ X, const float* __restrict__ RES,
                      const float* __restrict__ g, const float* __restrict__ be,
                      float* __restrict__ OUT)
{
  __shared__ float red4[4];
  const int row = blockIdx.x, tid = threadIdx.x;
  const size_t base = (size_t)row * Dc + tid * 4;
  const float4 xv = *(const float4*)(X + base);
  float s = xv.x + xv.y + xv.z + xv.w;
  s = block_sum(s, red4);
  const float mean = s * (1.0f / Dc);
  const float d0 = xv.x-mean, d1 = xv.y-mean, d2 = xv.z-mean, d3 = xv.w-mean;
  float ss = d0*d0 + d1*d1 + d2*d2 + d3*d3;
  ss = block_sum(ss, red4);
  const float rstd = rsqrtf(ss * (1.0f / Dc) + 1e-5f);
  const int c = tid * 4;
  const float4 rv = *(const float4*)(RES + base);
  float4 o;
  o.x = rv.x + d0*rstd*ldf(g+c+0) + ldf(be+c+0);
  o.y = rv.y + d1*rstd*ldf(g+c+1) + ldf(be+c+1);
  o.z = rv.z + d2*rstd*ldf(g+c+2) + ldf(be+c+2);
  o.w = rv.w + d3*rstd*ldf(g+c+3) + ldf(be+c+3);
  *(float4*)(OUT + base) = o;
}

__global__ __launch_bounds__(256)   // OUT = ln(X + Y)
void ln_sum_kernel(const float* __restrict__ X, const float* __restrict__ Y,
                   const float* __restrict__ g, const float* __restrict__ be,
                   float* __restrict__ OUT)
{
  __shared__ float red4[4];
  const int row = blockIdx.x, tid = threadIdx.x;
  const size_t base = (size_t)row * Dc + tid * 4;
  const float4 xv = *(const float4*)(X + base);
  const float4 yv = *(const float4*)(Y + base);
  const float x0 = xv.x+yv.x, x1 = xv.y+yv.y, x2 = xv.z+yv.z, x3 = xv.w+yv.w;
  float s = x0 + x1 + x2 + x3;
  s = block_sum(s, red4);
  const float mean = s * (1.0f / Dc);
  const float d0 = x0-mean, d1 = x1-mean, d2 = x2-mean, d3 = x3-mean;
  float ss = d0*d0 + d1*d1 + d2*d2 + d3*d3;
  ss = block_sum(ss, red4);
  const float rstd = rsqrtf(ss * (1.0f / Dc) + 1e-5f);
  const int c = tid * 4;
  float4 o;
  o.x = d0*rstd*ldf(g+c+0) + ldf(be+c+0);
  o.y = d1*rstd*ldf(g+c+1) + ldf(be+c+1);
  o.z = d2*rstd*ldf(g+c+2) + ldf(be+c+2);
  o.w = d3*rstd*ldf(g+c+3) + ldf(be+c+3);
  *(float4*)(OUT + base) = o;
}

// ---------- GLU: hg[t,d] = h1[t,d] * sigmoid(h1[t,D+d]) ----------
__global__ __launch_bounds__(256)
void glu_kernel(const float* __restrict__ H1, float* __restrict__ HG)
{
  const int gid = blockIdx.x * 256 + threadIdx.x;  // TD/4 total
  const int t = gid >> 8;
  const int c4 = (gid & 255) * 4;
  const float* p = H1 + (size_t)t * (2 * Dc);
  const float4 a = *(const float4*)(p + c4);
  const float4 gg = *(const float4*)(p + Dc + c4);
  float4 o;
  o.x = a.x / (1.0f + expf(-gg.x));
  o.y = a.y / (1.0f + expf(-gg.y));
  o.z = a.z / (1.0f + expf(-gg.z));
  o.w = a.w / (1.0f + expf(-gg.w));
  *(float4*)(HG + (size_t)t * Dc + c4) = o;
}

// ---------- depthwise conv K=5 (+bias, bn-scale, hardswish), [B,L,D] layout ----
__global__ __launch_bounds__(256)
void dwconv_kernel(const float* __restrict__ HG, const float* __restrict__ w,
                   const float* __restrict__ wb, const float* __restrict__ gn,
                   const float* __restrict__ bb, float* __restrict__ OUT)
{
  const int gid = blockIdx.x * 256 + threadIdx.x;  // TD total
  const int d = gid & (Dc - 1);
  const int l = (gid >> 10) & (Lc - 1);
  const int b = gid >> 21;
  const size_t rowb = (size_t)b * Lc;
  float acc = ldf(wb + d);
  #pragma unroll
  for (int s = 0; s < 5; s++) {
    const int lp = l + 2 - s;
    if (lp >= 0 && lp < Lc)
      acc += ldf(w + d * 5 + s) * HG[((rowb + lp) << 10) + d];
  }
  const float rs = rsqrtf(1.0f + 1e-5f);
  const float t = acc * rs * ldf(gn + d) + ldf(bb + d);
  OUT[gid] = t * fminf(fmaxf(t + 3.0f, 0.0f), 6.0f) * (1.0f / 6.0f);
}

// =====================================================================
extern "C" void kernel_launch(void* const* d_in, const int* in_sizes, int n_in,
                              void* d_out, int out_size, void* d_ws, size_t ws_size,
                              hipStream_t stream) {
  (void)in_sizes; (void)n_in; (void)out_size; (void)ws_size;
  const float* mem    = (const float*)d_in[0];
  const float* wq     = (const float*)d_in[1];
  const float* bq     = (const float*)d_in[2];
  const float* wk     = (const float*)d_in[3];
  const float* bk     = (const float*)d_in[4];
  const float* wv     = (const float*)d_in[5];
  const float* bv     = (const float*)d_in[6];
  const float* wo     = (const float*)d_in[7];
  const float* bo     = (const float*)d_in[8];
  const float* n1g    = (const float*)d_in[9];
  const float* n1b    = (const float*)d_in[10];
  const float* clng   = (const float*)d_in[11];
  const float* clnb   = (const float*)d_in[12];
  const float* pw1w   = (const float*)d_in[13];
  const float* pw1b   = (const float*)d_in[14];
  const float* dww    = (const float*)d_in[15];
  const float* dwb    = (const float*)d_in[16];
  const float* bng    = (const float*)d_in[17];
  const float* bnb    = (const float*)d_in[18];
  const float* pw2w   = (const float*)d_in[19];
  const float* pw2b   = (const float*)d_in[20];
  const float* projw  = (const float*)d_in[21];
  const float* projb  = (const float*)d_in[22];
  const float* proj2w = (const float*)d_in[23];
  const float* proj2b = (const float*)d_in[24];
  const float* lin1w  = (const float*)d_in[25];
  const float* lin1b  = (const float*)d_in[26];
  const float* lin2w  = (const float*)d_in[27];
  const float* lin2b  = (const float*)d_in[28];
  const float* n3g    = (const float*)d_in[29];
  const float* n3b    = (const float*)d_in[30];
  float* out = (float*)d_out;

  float* ws   = (float*)d_ws;
  float* qb   = ws;            // q        -> later tgt2
  float* kb   = ws + TD;       // k        -> later mem1
  float* vb   = ws + 2*TD;     // v        -> later h_ln -> hc -> ffout
  float* ob   = ws + 3*TD;     // attn out -> later hg -> proj
  float* big1 = ws + 4*TD;     // h1[0:TD]  -> later mem2
  float* big2 = ws + 5*TD;     // h1[TD:2TD]-> later conv_out
  float* ffb  = ws + 6*TD;     // [NT,FF] = 4*TD
  // total workspace: 10*TD floats = 167.8 MB

  const dim3 blk(256);
  const long long LD = (long long)Lc * Dc;

  // --- attention ---
  gemm_kernel<false,EPI_BIAS><<<dim3(16,64,1),blk,0,stream>>>(mem,wq,bq,nullptr,qb,NT,Dc,Dc,0,0);
  gemm_kernel<false,EPI_BIAS><<<dim3(16,64,1),blk,0,stream>>>(mem,wk,bk,nullptr,kb,NT,Dc,Dc,0,0);
  gemm_kernel<false,EPI_BIAS><<<dim3(16,64,1),blk,0,stream>>>(mem,wv,bv,nullptr,vb,NT,Dc,Dc,0,0);
  rope_kernel<<<dim3(NT*Hc/256),blk,0,stream>>>(qb);
  rope_kernel<<<dim3(NT*Hc/256),blk,0,stream>>>(kb);
  attn_kernel<<<dim3(Lc, Bc*Hc),blk,0,stream>>>(qb,kb,vb,ob);
  gemm_kernel<false,EPI_BIAS><<<dim3(16,64,1),blk,0,stream>>>(ob,wo,bo,nullptr,qb,NT,Dc,Dc,0,0);
  // mem1 = mem + ln(tgt2)  -> kb
  ln_resadd_kernel<<<dim3(NT),blk,0,stream>>>(qb, mem, n1g, n1b, kb);

  // --- conv block ---
  ln_plain_kernel<<<dim3(NT),blk,0,stream>>>(kb, clng, clnb, vb);                 // h_ln -> vb
  gemm_kernel<false,EPI_BIAS><<<dim3(32,64,1),blk,0,stream>>>(vb,pw1w,pw1b,nullptr,big1,NT,2*Dc,Dc,0,0);
  glu_kernel<<<dim3((unsigned)(TD/4/256)),blk,0,stream>>>(big1, ob);              // hg -> ob
  dwconv_kernel<<<dim3((unsigned)(TD/256)),blk,0,stream>>>(ob, dww, dwb, bng, bnb, vb); // hc -> vb
  // conv_out = hc @ pw2 + pw2_b + mem1[b,0,:]  -> big2
  gemm_kernel<false,EPI_ADDROW0><<<dim3(16,64,1),blk,0,stream>>>(vb,pw2w,pw2b,kb,big2,NT,Dc,Dc,0,0);

  // --- proj path: proj[b,m,d] = sum_l proj_w[l,m]*mem1[b,l,d] + proj_b[m] ---
  gemm_kernel<true,EPI_BIAS_ROW><<<dim3(16,32,2),blk,0,stream>>>(projw,kb,projb,nullptr,ob,Lc,Dc,Lc,LD,LD);
  // mem2 = proj @ proj2_w + proj2_b + conv_out  -> big1
  gemm_kernel<false,EPI_ADD><<<dim3(16,64,1),blk,0,stream>>>(ob,proj2w,proj2b,big2,big1,NT,Dc,Dc,0,0);

  // --- feed-forward ---
  gemm_kernel<false,EPI_GELU><<<dim3(64,64,1),blk,0,stream>>>(big1,lin1w,lin1b,nullptr,ffb,NT,FFc,Dc,0,0);
  gemm_kernel<false,EPI_BIAS><<<dim3(16,64,1),blk,0,stream>>>(ffb,lin2w,lin2b,nullptr,vb,NT,Dc,FFc,0,0);

  // --- final: out = ln(mem2 + ffout) ---
  ln_sum_kernel<<<dim3(NT),blk,0,stream>>>(big1, vb, n3g, n3b, out);
}

// Round 3
// 3635.188 us; speedup vs baseline: 3.0221x; 3.0221x over previous
//
#include <hip/hip_runtime.h>
#include <hip/hip_bf16.h>
#include <math.h>

constexpr int Bc = 2, Lc = 2048, Dc = 1024, Hc = 16, HDc = 64, FFc = 4096;
constexpr int NT = Bc * Lc;              // 4096 tokens
constexpr size_t TD = (size_t)NT * Dc;   // 4194304 elements per [B,L,D] tensor

__device__ __forceinline__ float ldf(const float* p) { return *p; }

// ---------- block reductions (blockDim.x == 256 = 4 waves) ----------
__device__ __forceinline__ float block_sum(float v, float* red) {
  const int lane = threadIdx.x & 63, w = threadIdx.x >> 6;
  #pragma unroll
  for (int o = 32; o > 0; o >>= 1) v += __shfl_down(v, o, 64);
  __syncthreads();
  if (lane == 0) red[w] = v;
  __syncthreads();
  return red[0] + red[1] + red[2] + red[3];
}

// ---------- generic tiled fp32 GEMM: C[m,n] = sum_k A[m,k]*B[k,n] (+epilogue) ----
constexpr int EPI_BIAS = 0, EPI_BIAS_ROW = 1, EPI_GELU = 2, EPI_ADD = 3, EPI_ADDROW0 = 4;

template<bool TRANSA, int EPI>
__global__ __launch_bounds__(256)
void gemm_kernel(const float* __restrict__ A, const float* __restrict__ B,
                 const float* __restrict__ bias, const float* __restrict__ extra,
                 float* __restrict__ C, int M, int N, int Kd,
                 long long strideB, long long strideC)
{
  __shared__ float As[16][65];   // [k][m], padded
  __shared__ float Bs[16][64];   // [k][n]
  const int tid = threadIdx.x, tx = tid & 15, ty = tid >> 4;
  const int m0 = blockIdx.y * 64, n0 = blockIdx.x * 64;
  const float* Bp = B + (long long)blockIdx.z * strideB;
  float* Cp = C + (long long)blockIdx.z * strideC;
  float acc[4][4] = {};

  for (int k0 = 0; k0 < Kd; k0 += 16) {
    #pragma unroll
    for (int i = 0; i < 4; i++) {
      const int idx = tid + i * 256;
      if (TRANSA) {
        const int kk = idx >> 6, mm = idx & 63;
        As[kk][mm] = ldf(A + (long long)(k0 + kk) * M + (m0 + mm));
      } else {
        const int r = idx >> 4, c = idx & 15;
        As[c][r] = ldf(A + (long long)(m0 + r) * Kd + (k0 + c));
      }
    }
    #pragma unroll
    for (int i = 0; i < 4; i++) {
      const int idx = tid + i * 256;
      const int kk = idx >> 6, nn = idx & 63;
      Bs[kk][nn] = ldf(Bp + (long long)(k0 + kk) * N + (n0 + nn));
    }
    __syncthreads();
    #pragma unroll
    for (int kk = 0; kk < 16; kk++) {
      const float a0 = As[kk][ty*4+0], a1 = As[kk][ty*4+1];
      const float a2 = As[kk][ty*4+2], a3 = As[kk][ty*4+3];
      const float4 b4 = *(const float4*)&Bs[kk][tx*4];
      acc[0][0] += a0*b4.x; acc[0][1] += a0*b4.y; acc[0][2] += a0*b4.z; acc[0][3] += a0*b4.w;
      acc[1][0] += a1*b4.x; acc[1][1] += a1*b4.y; acc[1][2] += a1*b4.z; acc[1][3] += a1*b4.w;
      acc[2][0] += a2*b4.x; acc[2][1] += a2*b4.y; acc[2][2] += a2*b4.z; acc[2][3] += a2*b4.w;
      acc[3][0] += a3*b4.x; acc[3][1] += a3*b4.y; acc[3][2] += a3*b4.z; acc[3][3] += a3*b4.w;
    }
    __syncthreads();
  }

  #pragma unroll
  for (int i = 0; i < 4; i++) {
    const int m = m0 + ty * 4 + i;
    const int n = n0 + tx * 4;
    float r0 = acc[i][0], r1 = acc[i][1], r2 = acc[i][2], r3 = acc[i][3];
    if constexpr (EPI == EPI_BIAS || EPI == EPI_GELU || EPI == EPI_ADD || EPI == EPI_ADDROW0) {
      r0 += ldf(bias + n + 0); r1 += ldf(bias + n + 1);
      r2 += ldf(bias + n + 2); r3 += ldf(bias + n + 3);
    }
    if constexpr (EPI == EPI_BIAS_ROW) {
      const float bm = ldf(bias + m);
      r0 += bm; r1 += bm; r2 += bm; r3 += bm;
    }
    if constexpr (EPI == EPI_GELU) {
      r0 = 0.5f * r0 * (1.0f + erff(r0 * 0.70710678118654752f));
      r1 = 0.5f * r1 * (1.0f + erff(r1 * 0.70710678118654752f));
      r2 = 0.5f * r2 * (1.0f + erff(r2 * 0.70710678118654752f));
      r3 = 0.5f * r3 * (1.0f + erff(r3 * 0.70710678118654752f));
    }
    if constexpr (EPI == EPI_ADD) {
      const float* e = extra + (size_t)m * N + n;
      r0 += e[0]; r1 += e[1]; r2 += e[2]; r3 += e[3];
    }
    if constexpr (EPI == EPI_ADDROW0) {
      const float* e = extra + (size_t)(m >> 11) * ((size_t)Lc * Dc) + n;
      r0 += e[0]; r1 += e[1]; r2 += e[2]; r3 += e[3];
    }
    *(float4*)(Cp + (size_t)m * N + n) = make_float4(r0, r1, r2, r3);
  }
}

// ---------- RoPE (reference's even/odd -> concat layout), in-place ----------
__global__ __launch_bounds__(256)
void rope_kernel(float* __restrict__ X)
{
  const int gid = blockIdx.x * 256 + threadIdx.x;  // one thread = one (token, head)
  if (gid >= NT * Hc) return;
  const int h = gid & (Hc - 1);
  const int token = gid >> 4;
  const int l = token & (Lc - 1);
  float* p = X + (size_t)token * Dc + h * HDc;
  float x[64], out[64];
  #pragma unroll
  for (int i = 0; i < 16; i++) *(float4*)&x[4*i] = *(const float4*)&p[4*i];
  const float lf = (float)l;
  #pragma unroll
  for (int i = 0; i < 32; i++) {
    const int j = (i < 16) ? (2 * i) : (2 * (i - 16));
    const float a0 = lf * powf(10000.0f, -(float)j       / 32.0f);
    const float a1 = lf * powf(10000.0f, -(float)(j + 1) / 32.0f);
    float c, s;
    if (i < 16) { c = cosf(a0); s = cosf(a1); }
    else        { c = sinf(a0); s = sinf(a1); }
    out[i]      = x[2*i] * c - x[2*i+1] * s;
    out[32 + i] = x[2*i] * s + x[2*i+1] * c;
  }
  #pragma unroll
  for (int i = 0; i < 16; i++) *(float4*)&p[4*i] = *(const float4*)&out[4*i];
}

// ---------- flash attention: one block per (64-q-tile, b*H+h) ----------
// S = Q K^T (reg-tiled), online softmax in registers (shfl over tx-group),
// O += P V (reg-tiled). K-buffer reused for P (barrier-separated).
// LDS layouts (all 64x64 fp32, XOR-swizzled for conflict-free b128 access):
//   Qt[d][q ^ 4*(d>>2)]   KP: K as [d][k ^ 4*(d>>2)], later P as [k][q ^ 4*(k>>2)]
//   Vs[k][d]  (natural)
__global__ __launch_bounds__(256)
void flash_attn_kernel(const float* __restrict__ Q, const float* __restrict__ K,
                       const float* __restrict__ V, float* __restrict__ O)
{
  __shared__ float Qt[64 * 64];
  __shared__ float KP[64 * 64];
  __shared__ float Vs[64 * 64];
  const int tid = threadIdx.x;
  const int tx = tid & 15, ty = tid >> 4;
  const int q0 = blockIdx.x * 64;
  const int bh = blockIdx.y;
  const int b = bh >> 4, h = bh & 15;
  const size_t hb = (size_t)b * Lc * Dc + (size_t)h * HDc;
  const float slope = exp2f(-0.5f * (float)h);

  // load Q tile -> transposed + swizzled
  #pragma unroll
  for (int i = 0; i < 4; i++) {
    const int idx = tid + i * 256;
    const int r = idx >> 4, dq = idx & 15;
    const float4 v4 = *(const float4*)(Q + hb + (size_t)(q0 + r) * Dc + dq * 4);
    const int col = r ^ (dq * 4);
    Qt[(dq*4+0)*64 + col] = v4.x;
    Qt[(dq*4+1)*64 + col] = v4.y;
    Qt[(dq*4+2)*64 + col] = v4.z;
    Qt[(dq*4+3)*64 + col] = v4.w;
  }

  float m_i[4], l_i[4], acc_o[4][4];
  #pragma unroll
  for (int i = 0; i < 4; i++) {
    m_i[i] = -3.0e38f; l_i[i] = 0.f;
    #pragma unroll
    for (int j = 0; j < 4; j++) acc_o[i][j] = 0.f;
  }

  for (int k0 = 0; k0 < Lc; k0 += 64) {
    __syncthreads();   // prev PV reads done before overwriting KP/Vs (also covers Q load)
    #pragma unroll
    for (int i = 0; i < 4; i++) {
      const int idx = tid + i * 256;
      const int r = idx >> 4, dq = idx & 15;
      const float4 kv = *(const float4*)(K + hb + (size_t)(k0 + r) * Dc + dq * 4);
      const int col = r ^ (dq * 4);
      KP[(dq*4+0)*64 + col] = kv.x;
      KP[(dq*4+1)*64 + col] = kv.y;
      KP[(dq*4+2)*64 + col] = kv.z;
      KP[(dq*4+3)*64 + col] = kv.w;
      *(float4*)&Vs[r * 64 + dq * 4] =
          *(const float4*)(V + hb + (size_t)(k0 + r) * Dc + dq * 4);
    }
    __syncthreads();

    // ---- S = Q K^T : acc[i][j] for (q=q0+4ty+i, k=k0+4tx+j) ----
    float acc[4][4] = {};
    #pragma unroll 8
    for (int d = 0; d < 64; d++) {
      const int swz = (d >> 2) * 4;
      const float4 a4 = *(const float4*)&Qt[d * 64 + ((ty * 4) ^ swz)];
      const float4 b4 = *(const float4*)&KP[d * 64 + ((tx * 4) ^ swz)];
      acc[0][0] += a4.x*b4.x; acc[0][1] += a4.x*b4.y; acc[0][2] += a4.x*b4.z; acc[0][3] += a4.x*b4.w;
      acc[1][0] += a4.y*b4.x; acc[1][1] += a4.y*b4.y; acc[1][2] += a4.y*b4.z; acc[1][3] += a4.y*b4.w;
      acc[2][0] += a4.z*b4.x; acc[2][1] += a4.z*b4.y; acc[2][2] += a4.z*b4.z; acc[2][3] += a4.z*b4.w;
      acc[3][0] += a4.w*b4.x; acc[3][1] += a4.w*b4.y; acc[3][2] += a4.w*b4.z; acc[3][3] += a4.w*b4.w;
    }

    // ---- online softmax (registers + shfl over the 16-lane tx group) ----
    float p[4][4];
    #pragma unroll
    for (int i = 0; i < 4; i++) {
      const float qg = (float)(q0 + ty * 4 + i);
      float sv[4], tmax = -3.0e38f;
      #pragma unroll
      for (int j = 0; j < 4; j++) {
        const float kg = (float)(k0 + tx * 4 + j);
        sv[j] = acc[i][j] * 0.125f + slope * fmaxf(qg - kg, 0.0f);
        tmax = fmaxf(tmax, sv[j]);
      }
      #pragma unroll
      for (int mk = 1; mk < 16; mk <<= 1) tmax = fmaxf(tmax, __shfl_xor(tmax, mk, 64));
      const float mnew = fmaxf(m_i[i], tmax);
      const float alpha = expf(m_i[i] - mnew);
      float rsum = 0.f;
      #pragma unroll
      for (int j = 0; j < 4; j++) { p[i][j] = expf(sv[j] - mnew); rsum += p[i][j]; }
      #pragma unroll
      for (int mk = 1; mk < 16; mk <<= 1) rsum += __shfl_xor(rsum, mk, 64);
      l_i[i] = l_i[i] * alpha + rsum;
      m_i[i] = mnew;
      #pragma unroll
      for (int j = 0; j < 4; j++) acc_o[i][j] *= alpha;
    }

    __syncthreads();   // all S-GEMM reads of KP(K) done
    #pragma unroll
    for (int i = 0; i < 4; i++)
      #pragma unroll
      for (int j = 0; j < 4; j++)
        KP[(tx*4+j)*64 + (((ty*4+i)) ^ (tx*4))] = p[i][j];
    __syncthreads();   // P visible

    // ---- O += P V : acc_o[i][jj] for (q=q0+4ty+i, d=4tx+jj) ----
    #pragma unroll 8
    for (int kk = 0; kk < 64; kk++) {
      const int swz = (kk >> 2) * 4;
      const float4 a4 = *(const float4*)&KP[kk * 64 + ((ty * 4) ^ swz)];
      const float4 b4 = *(const float4*)&Vs[kk * 64 + tx * 4];
      acc_o[0][0] += a4.x*b4.x; acc_o[0][1] += a4.x*b4.y; acc_o[0][2] += a4.x*b4.z; acc_o[0][3] += a4.x*b4.w;
      acc_o[1][0] += a4.y*b4.x; acc_o[1][1] += a4.y*b4.y; acc_o[1][2] += a4.y*b4.z; acc_o[1][3] += a4.y*b4.w;
      acc_o[2][0] += a4.z*b4.x; acc_o[2][1] += a4.z*b4.y; acc_o[2][2] += a4.z*b4.z; acc_o[2][3] += a4.z*b4.w;
      acc_o[3][0] += a4.w*b4.x; acc_o[3][1] += a4.w*b4.y; acc_o[3][2] += a4.w*b4.z; acc_o[3][3] += a4.w*b4.w;
    }
  }

  #pragma unroll
  for (int i = 0; i < 4; i++) {
    const float inv = 1.0f / l_i[i];
    float4 o = make_float4(acc_o[i][0]*inv, acc_o[i][1]*inv, acc_o[i][2]*inv, acc_o[i][3]*inv);
    *(float4*)(O + hb + (size_t)(q0 + ty * 4 + i) * Dc + tx * 4) = o;
  }
}

// ---------- layernorm variants (one block per row, D=1024, 4 elems/thread) ----
__global__ __launch_bounds__(256)
void ln_plain_kernel(const float* __restrict__ X, const float* __restrict__ g,
                     const float* __restrict__ be, float* __restrict__ OUT)
{
  __shared__ float red4[4];
  const int row = blockIdx.x, tid = threadIdx.x;
  const size_t base = (size_t)row * Dc + tid * 4;
  const float4 xv = *(const float4*)(X + base);
  float s = xv.x + xv.y + xv.z + xv.w;
  s = block_sum(s, red4);
  const float mean = s * (1.0f / Dc);
  const float d0 = xv.x-mean, d1 = xv.y-mean, d2 = xv.z-mean, d3 = xv.w-mean;
  float ss = d0*d0 + d1*d1 + d2*d2 + d3*d3;
  ss = block_sum(ss, red4);
  const float rstd = rsqrtf(ss * (1.0f / Dc) + 1e-5f);
  const int c = tid * 4;
  float4 o;
  o.x = d0*rstd*ldf(g+c+0) + ldf(be+c+0);
  o.y = d1*rstd*ldf(g+c+1) + ldf(be+c+1);
  o.z = d2*rstd*ldf(g+c+2) + ldf(be+c+2);
  o.w = d3*rstd*ldf(g+c+3) + ldf(be+c+3);
  *(float4*)(OUT + base) = o;
}

__global__ __launch_bounds__(256)   // OUT = RES + ln(X)
void ln_resadd_kernel(const float* __restrict__ X, const float* __restrict__ RES,
                      const float* __restrict__ g, const float* __restrict__ be,
                      float* __restrict__ OUT)
{
  __shared__ float red4[4];
  const int row = blockIdx.x, tid = threadIdx.x;
  const size_t base = (size_t)row * Dc + tid * 4;
  const float4 xv = *(const float4*)(X + base);
  float s = xv.x + xv.y + xv.z + xv.w;
  s = block_sum(s, red4);
  const float mean = s * (1.0f / Dc);
  const float d0 = xv.x-mean, d1 = xv.y-mean, d2 = xv.z-mean, d3 = xv.w-mean;
  float ss = d0*d0 + d1*d1 + d2*d2 + d3*d3;
  ss = block_sum(ss, red4);
  const float rstd = rsqrtf(ss * (1.0f / Dc) + 1e-5f);
  const int c = tid * 4;
  const float4 rv = *(const float4*)(RES + base);
  float4 o;
  o.x = rv.x + d0*rstd*ldf(g+c+0) + ldf(be+c+0);
  o.y = rv.y + d1*rstd*ldf(g+c+1) + ldf(be+c+1);
  o.z = rv.z + d2*rstd*ldf(g+c+2) + ldf(be+c+2);
  o.w = rv.w + d3*rstd*ldf(g+c+3) + ldf(be+c+3);
  *(float4*)(OUT + base) = o;
}

__global__ __launch_bounds__(256)   // OUT = ln(X + Y)
void ln_sum_kernel(const float* __restrict__ X, const float* __restrict__ Y,
                   const float* __restrict__ g, const float* __restrict__ be,
                   float* __restrict__ OUT)
{
  __shared__ float red4[4];
  const int row = blockIdx.x, tid = threadIdx.x;
  const size_t base = (size_t)row * Dc + tid * 4;
  const float4 xv = *(const float4*)(X + base);
  const float4 yv = *(const float4*)(Y + base);
  const float x0 = xv.x+yv.x, x1 = xv.y+yv.y, x2 = xv.z+yv.z, x3 = xv.w+yv.w;
  float s = x0 + x1 + x2 + x3;
  s = block_sum(s, red4);
  const float mean = s * (1.0f / Dc);
  const float d0 = x0-mean, d1 = x1-mean, d2 = x2-mean, d3 = x3-mean;
  float ss = d0*d0 + d1*d1 + d2*d2 + d3*d3;
  ss = block_sum(ss, red4);
  const float rstd = rsqrtf(ss * (1.0f / Dc) + 1e-5f);
  const int c = tid * 4;
  float4 o;
  o.x = d0*rstd*ldf(g+c+0) + ldf(be+c+0);
  o.y = d1*rstd*ldf(g+c+1) + ldf(be+c+1);
  o.z = d2*rstd*ldf(g+c+2) + ldf(be+c+2);
  o.w = d3*rstd*ldf(g+c+3) + ldf(be+c+3);
  *(float4*)(OUT + base) = o;
}

// ---------- GLU: hg[t,d] = h1[t,d] * sigmoid(h1[t,D+d]) ----------
__global__ __launch_bounds__(256)
void glu_kernel(const float* __restrict__ H1, float* __restrict__ HG)
{
  const int gid = blockIdx.x * 256 + threadIdx.x;  // TD/4 total
  const int t = gid >> 8;
  const int c4 = (gid & 255) * 4;
  const float* p = H1 + (size_t)t * (2 * Dc);
  const float4 a = *(const float4*)(p + c4);
  const float4 gg = *(const float4*)(p + Dc + c4);
  float4 o;
  o.x = a.x / (1.0f + expf(-gg.x));
  o.y = a.y / (1.0f + expf(-gg.y));
  o.z = a.z / (1.0f + expf(-gg.z));
  o.w = a.w / (1.0f + expf(-gg.w));
  *(float4*)(HG + (size_t)t * Dc + c4) = o;
}

// ---------- depthwise conv K=5 (+bias, bn-scale, hardswish), [B,L,D] layout ----
__global__ __launch_bounds__(256)
void dwconv_kernel(const float* __restrict__ HG, const float* __restrict__ w,
                   const float* __restrict__ wb, const float* __restrict__ gn,
                   const float* __restrict__ bb, float* __restrict__ OUT)
{
  const int gid = blockIdx.x * 256 + threadIdx.x;  // TD total
  const int d = gid & (Dc - 1);
  const int l = (gid >> 10) & (Lc - 1);
  const int b = gid >> 21;
  const size_t rowb = (size_t)b * Lc;
  float acc = ldf(wb + d);
  #pragma unroll
  for (int s = 0; s < 5; s++) {
    const int lp = l + 2 - s;
    if (lp >= 0 && lp < Lc)
      acc += ldf(w + d * 5 + s) * HG[((rowb + lp) << 10) + d];
  }
  const float rs = rsqrtf(1.0f + 1e-5f);
  const float t = acc * rs * ldf(gn + d) + ldf(bb + d);
  OUT[gid] = t * fminf(fmaxf(t + 3.0f, 0.0f), 6.0f) * (1.0f / 6.0f);
}

// =====================================================================
extern "C" void kernel_launch(void* const* d_in, const int* in_sizes, int n_in,
                              void* d_out, int out_size, void* d_ws, size_t ws_size,
                              hipStream_t stream) {
  (void)in_sizes; (void)n_in; (void)out_size; (void)ws_size;
  const float* mem    = (const float*)d_in[0];
  const float* wq     = (const float*)d_in[1];
  const float* bq     = (const float*)d_in[2];
  const float* wk     = (const float*)d_in[3];
  const float* bk     = (const float*)d_in[4];
  const float* wv     = (const float*)d_in[5];
  const float* bv     = (const float*)d_in[6];
  const float* wo     = (const float*)d_in[7];
  const float* bo     = (const float*)d_in[8];
  const float* n1g    = (const float*)d_in[9];
  const float* n1b    = (const float*)d_in[10];
  const float* clng   = (const float*)d_in[11];
  const float* clnb   = (const float*)d_in[12];
  const float* pw1w   = (const float*)d_in[13];
  const float* pw1b   = (const float*)d_in[14];
  const float* dww    = (const float*)d_in[15];
  const float* dwb    = (const float*)d_in[16];
  const float* bng    = (const float*)d_in[17];
  const float* bnb    = (const float*)d_in[18];
  const float* pw2w   = (const float*)d_in[19];
  const float* pw2b   = (const float*)d_in[20];
  const float* projw  = (const float*)d_in[21];
  const float* projb  = (const float*)d_in[22];
  const float* proj2w = (const float*)d_in[23];
  const float* proj2b = (const float*)d_in[24];
  const float* lin1w  = (const float*)d_in[25];
  const float* lin1b  = (const float*)d_in[26];
  const float* lin2w  = (const float*)d_in[27];
  const float* lin2b  = (const float*)d_in[28];
  const float* n3g    = (const float*)d_in[29];
  const float* n3b    = (const float*)d_in[30];
  float* out = (float*)d_out;

  float* ws   = (float*)d_ws;
  float* qb   = ws;            // q        -> later tgt2
  float* kb   = ws + TD;       // k        -> later mem1
  float* vb   = ws + 2*TD;     // v        -> later h_ln -> hc -> ffout
  float* ob   = ws + 3*TD;     // attn out -> later hg -> proj
  float* big1 = ws + 4*TD;     // h1[0:TD]  -> later mem2
  float* big2 = ws + 5*TD;     // h1[TD:2TD]-> later conv_out
  float* ffb  = ws + 6*TD;     // [NT,FF] = 4*TD
  // total workspace: 10*TD floats = 167.8 MB

  const dim3 blk(256);
  const long long LD = (long long)Lc * Dc;

  // --- attention ---
  gemm_kernel<false,EPI_BIAS><<<dim3(16,64,1),blk,0,stream>>>(mem,wq,bq,nullptr,qb,NT,Dc,Dc,0,0);
  gemm_kernel<false,EPI_BIAS><<<dim3(16,64,1),blk,0,stream>>>(mem,wk,bk,nullptr,kb,NT,Dc,Dc,0,0);
  gemm_kernel<false,EPI_BIAS><<<dim3(16,64,1),blk,0,stream>>>(mem,wv,bv,nullptr,vb,NT,Dc,Dc,0,0);
  rope_kernel<<<dim3(NT*Hc/256),blk,0,stream>>>(qb);
  rope_kernel<<<dim3(NT*Hc/256),blk,0,stream>>>(kb);
  flash_attn_kernel<<<dim3(Lc/64, Bc*Hc),blk,0,stream>>>(qb,kb,vb,ob);
  gemm_kernel<false,EPI_BIAS><<<dim3(16,64,1),blk,0,stream>>>(ob,wo,bo,nullptr,qb,NT,Dc,Dc,0,0);
  // mem1 = mem + ln(tgt2)  -> kb
  ln_resadd_kernel<<<dim3(NT),blk,0,stream>>>(qb, mem, n1g, n1b, kb);

  // --- conv block ---
  ln_plain_kernel<<<dim3(NT),blk,0,stream>>>(kb, clng, clnb, vb);                 // h_ln -> vb
  gemm_kernel<false,EPI_BIAS><<<dim3(32,64,1),blk,0,stream>>>(vb,pw1w,pw1b,nullptr,big1,NT,2*Dc,Dc,0,0);
  glu_kernel<<<dim3((unsigned)(TD/4/256)),blk,0,stream>>>(big1, ob);              // hg -> ob
  dwconv_kernel<<<dim3((unsigned)(TD/256)),blk,0,stream>>>(ob, dww, dwb, bng, bnb, vb); // hc -> vb
  // conv_out = hc @ pw2 + pw2_b + mem1[b,0,:]  -> big2
  gemm_kernel<false,EPI_ADDROW0><<<dim3(16,64,1),blk,0,stream>>>(vb,pw2w,pw2b,kb,big2,NT,Dc,Dc,0,0);

  // --- proj path: proj[b,m,d] = sum_l proj_w[l,m]*mem1[b,l,d] + proj_b[m] ---
  gemm_kernel<true,EPI_BIAS_ROW><<<dim3(16,32,2),blk,0,stream>>>(projw,kb,projb,nullptr,ob,Lc,Dc,Lc,LD,LD);
  // mem2 = proj @ proj2_w + proj2_b + conv_out  -> big1
  gemm_kernel<false,EPI_ADD><<<dim3(16,64,1),blk,0,stream>>>(ob,proj2w,proj2b,big2,big1,NT,Dc,Dc,0,0);

  // --- feed-forward ---
  gemm_kernel<false,EPI_GELU><<<dim3(64,64,1),blk,0,stream>>>(big1,lin1w,lin1b,nullptr,ffb,NT,FFc,Dc,0,0);
  gemm_kernel<false,EPI_BIAS><<<dim3(16,64,1),blk,0,stream>>>(ffb,lin2w,lin2b,nullptr,vb,NT,Dc,FFc,0,0);

  // --- final: out = ln(mem2 + ffout) ---
  ln_sum_kernel<<<dim3(NT),blk,0,stream>>>(big1, vb, n3g, n3b, out);
}

// Round 4
// 1433.451 us; speedup vs baseline: 7.6639x; 2.5360x over previous
//
#include <hip/hip_runtime.h>
#include <hip/hip_bf16.h>
#include <math.h>

constexpr int Bc = 2, Lc = 2048, Dc = 1024, Hc = 16, HDc = 64, FFc = 4096;
constexpr int NT = Bc * Lc;              // 4096 tokens
constexpr size_t TD = (size_t)NT * Dc;   // 4194304 elements per [B,L,D] tensor
constexpr size_t MEG = 1024 * 1024;

__device__ __forceinline__ float ldf(const float* p) { return *p; }
__device__ __forceinline__ unsigned short f2b(float f) {
  __hip_bfloat16 h = __float2bfloat16(f);
  return *reinterpret_cast<unsigned short*>(&h);
}

using frag   = __attribute__((ext_vector_type(8))) short;   // 8 bf16 (4 VGPRs)
using f32x4v = __attribute__((ext_vector_type(4))) float;   // MFMA C/D

// ---------- block reductions (blockDim.x == 256 = 4 waves) ----------
__device__ __forceinline__ float block_sum(float v, float* red) {
  const int lane = threadIdx.x & 63, w = threadIdx.x >> 6;
  #pragma unroll
  for (int o = 32; o > 0; o >>= 1) v += __shfl_down(v, o, 64);
  __syncthreads();
  if (lane == 0) red[w] = v;
  __syncthreads();
  return red[0] + red[1] + red[2] + red[3];
}

// ---------- fp32 -> bf16 convert (same layout) ----------
__global__ __launch_bounds__(256)
void convert_bf16_kernel(const float* __restrict__ IN, unsigned short* __restrict__ OUT)
{
  const size_t gid = (size_t)blockIdx.x * 256 + threadIdx.x;
  const float4 v = *(const float4*)(IN + gid * 4);
  ushort4 o;
  o.x = f2b(v.x); o.y = f2b(v.y); o.z = f2b(v.z); o.w = f2b(v.w);
  *(ushort4*)(OUT + gid * 4) = o;
}

// ---------- fp32 [R,C] -> bf16 [C,R] transpose-convert ----------
__global__ __launch_bounds__(256)
void transpose_convert_kernel(const float* __restrict__ IN, unsigned short* __restrict__ OUT,
                              int R, int C, long long sIn, long long sOut)
{
  __shared__ float tile[64][65];
  const int t = threadIdx.x;
  const float* in = IN + (long long)blockIdx.z * sIn;
  unsigned short* out = OUT + (long long)blockIdx.z * sOut;
  const int r0 = blockIdx.y * 64, c0 = blockIdx.x * 64;
  #pragma unroll
  for (int i = 0; i < 4; i++) {
    const int r = (t >> 4) + i * 16, c4 = (t & 15) * 4;
    const float4 v = *(const float4*)(in + (size_t)(r0 + r) * C + c0 + c4);
    tile[r][c4+0] = v.x; tile[r][c4+1] = v.y; tile[r][c4+2] = v.z; tile[r][c4+3] = v.w;
  }
  __syncthreads();
  #pragma unroll
  for (int i = 0; i < 4; i++) {
    const int cc = (t >> 4) + i * 16, rr4 = (t & 15) * 4;
    ushort4 o;
    o.x = f2b(tile[rr4+0][cc]); o.y = f2b(tile[rr4+1][cc]);
    o.z = f2b(tile[rr4+2][cc]); o.w = f2b(tile[rr4+3][cc]);
    *(ushort4*)(out + (size_t)(c0 + cc) * R + r0 + rr4) = o;
  }
}

// ---------- MFMA bf16 GEMM: C[m,n] = sum_k A[m,k] * Bt[n,k] (+epilogue) ----
// A: [M,K] bf16 row-major. Bt: [N,K] bf16 row-major (i.e. B transposed).
// 128x128 tile, BK=32, 4 waves of 64x64, 16x16x32 MFMA.
constexpr int EPI_BIAS = 0, EPI_BIAS_ROW = 1, EPI_GELU = 2, EPI_ADD = 3, EPI_ADDROW0 = 4;

template<int EPI, bool OUTBF>
__global__ __launch_bounds__(256)
void mfma_gemm_kernel(const unsigned short* __restrict__ A, const unsigned short* __restrict__ Bt,
                      const float* __restrict__ bias, const float* __restrict__ extra,
                      float* __restrict__ C, unsigned short* __restrict__ Cbf,
                      int M, int N, int K,
                      long long sA, long long sB, long long sC)
{
  __shared__ unsigned short As[4][128][8];   // [k-granule][row m][8 bf16]
  __shared__ unsigned short Bs[4][128][8];   // [k-granule][row n][8 bf16]
  const int tid = threadIdx.x;
  const int l = tid & 63, w = tid >> 6;
  const int wm = (w & 1) * 64, wn = (w >> 1) * 64;
  const int m0 = blockIdx.y * 128, n0 = blockIdx.x * 128;
  const unsigned short* Ap = A + (long long)blockIdx.z * sA;
  const unsigned short* Bp = Bt + (long long)blockIdx.z * sB;

  f32x4v acc[4][4];
  #pragma unroll
  for (int mt = 0; mt < 4; mt++)
    #pragma unroll
    for (int nt = 0; nt < 4; nt++) acc[mt][nt] = {0.f, 0.f, 0.f, 0.f};

  const int gr = tid >> 2, gc = tid & 3;   // staging granule (row, k-chunk)
  const int c_ = l >> 4, rm = l & 15;      // fragment indices

  for (int k0 = 0; k0 < K; k0 += 32) {
    __syncthreads();
    const uint4 va0 = *(const uint4*)(Ap + (size_t)(m0 + gr)      * K + k0 + gc * 8);
    const uint4 va1 = *(const uint4*)(Ap + (size_t)(m0 + gr + 64) * K + k0 + gc * 8);
    const uint4 vb0 = *(const uint4*)(Bp + (size_t)(n0 + gr)      * K + k0 + gc * 8);
    const uint4 vb1 = *(const uint4*)(Bp + (size_t)(n0 + gr + 64) * K + k0 + gc * 8);
    *(uint4*)&As[gc][gr][0]      = va0;
    *(uint4*)&As[gc][gr + 64][0] = va1;
    *(uint4*)&Bs[gc][gr][0]      = vb0;
    *(uint4*)&Bs[gc][gr + 64][0] = vb1;
    __syncthreads();

    frag af[4], bfr[4];
    #pragma unroll
    for (int mt = 0; mt < 4; mt++) af[mt]  = *(const frag*)&As[c_][wm + mt * 16 + rm][0];
    #pragma unroll
    for (int nt = 0; nt < 4; nt++) bfr[nt] = *(const frag*)&Bs[c_][wn + nt * 16 + rm][0];
    #pragma unroll
    for (int mt = 0; mt < 4; mt++)
      #pragma unroll
      for (int nt = 0; nt < 4; nt++)
        acc[mt][nt] = __builtin_amdgcn_mfma_f32_16x16x32_bf16(af[mt], bfr[nt], acc[mt][nt], 0, 0, 0);
  }

  float* Cp = C + (long long)blockIdx.z * sC;
  unsigned short* Cbp = Cbf + (long long)blockIdx.z * sC;
  #pragma unroll
  for (int mt = 0; mt < 4; mt++) {
    #pragma unroll
    for (int nt = 0; nt < 4; nt++) {
      #pragma unroll
      for (int i = 0; i < 4; i++) {
        const int m = m0 + wm + mt * 16 + c_ * 4 + i;   // C/D: row=(lane>>4)*4+reg
        const int n = n0 + wn + nt * 16 + rm;           //      col=lane&15
        float r = acc[mt][nt][i];
        if constexpr (EPI == EPI_BIAS || EPI == EPI_GELU || EPI == EPI_ADD || EPI == EPI_ADDROW0)
          r += ldf(bias + n);
        if constexpr (EPI == EPI_BIAS_ROW) r += ldf(bias + m);
        if constexpr (EPI == EPI_GELU)
          r = 0.5f * r * (1.0f + erff(r * 0.70710678118654752f));
        if constexpr (EPI == EPI_ADD) r += extra[(size_t)m * N + n];
        if constexpr (EPI == EPI_ADDROW0) r += extra[(size_t)(m >> 11) * ((size_t)Lc * Dc) + n];
        if constexpr (OUTBF) Cbp[(size_t)m * N + n] = f2b(r);
        else                 Cp[(size_t)m * N + n] = r;
      }
    }
  }
}

// ---------- RoPE (reference's even/odd -> concat layout), in-place ----------
__global__ __launch_bounds__(256)
void rope_kernel(float* __restrict__ X)
{
  const int gid = blockIdx.x * 256 + threadIdx.x;  // one thread = one (token, head)
  if (gid >= NT * Hc) return;
  const int h = gid & (Hc - 1);
  const int token = gid >> 4;
  const int l = token & (Lc - 1);
  float* p = X + (size_t)token * Dc + h * HDc;
  float x[64], out[64];
  #pragma unroll
  for (int i = 0; i < 16; i++) *(float4*)&x[4*i] = *(const float4*)&p[4*i];
  const float lf = (float)l;
  #pragma unroll
  for (int i = 0; i < 32; i++) {
    const int j = (i < 16) ? (2 * i) : (2 * (i - 16));
    const float a0 = lf * powf(10000.0f, -(float)j       / 32.0f);
    const float a1 = lf * powf(10000.0f, -(float)(j + 1) / 32.0f);
    float c, s;
    if (i < 16) { c = cosf(a0); s = cosf(a1); }
    else        { c = sinf(a0); s = sinf(a1); }
    out[i]      = x[2*i] * c - x[2*i+1] * s;
    out[32 + i] = x[2*i] * s + x[2*i+1] * c;
  }
  #pragma unroll
  for (int i = 0; i < 16; i++) *(float4*)&p[4*i] = *(const float4*)&out[4*i];
}

// ---------- flash attention: one block per (64-q-tile, b*H+h) ----------
__global__ __launch_bounds__(256)
void flash_attn_kernel(const float* __restrict__ Q, const float* __restrict__ K,
                       const float* __restrict__ V, float* __restrict__ O)
{
  __shared__ float Qt[64 * 64];
  __shared__ float KP[64 * 64];
  __shared__ float Vs[64 * 64];
  const int tid = threadIdx.x;
  const int tx = tid & 15, ty = tid >> 4;
  const int q0 = blockIdx.x * 64;
  const int bh = blockIdx.y;
  const int b = bh >> 4, h = bh & 15;
  const size_t hb = (size_t)b * Lc * Dc + (size_t)h * HDc;
  const float slope = exp2f(-0.5f * (float)h);

  #pragma unroll
  for (int i = 0; i < 4; i++) {
    const int idx = tid + i * 256;
    const int r = idx >> 4, dq = idx & 15;
    const float4 v4 = *(const float4*)(Q + hb + (size_t)(q0 + r) * Dc + dq * 4);
    const int col = r ^ (dq * 4);
    Qt[(dq*4+0)*64 + col] = v4.x;
    Qt[(dq*4+1)*64 + col] = v4.y;
    Qt[(dq*4+2)*64 + col] = v4.z;
    Qt[(dq*4+3)*64 + col] = v4.w;
  }

  float m_i[4], l_i[4], acc_o[4][4];
  #pragma unroll
  for (int i = 0; i < 4; i++) {
    m_i[i] = -3.0e38f; l_i[i] = 0.f;
    #pragma unroll
    for (int j = 0; j < 4; j++) acc_o[i][j] = 0.f;
  }

  for (int k0 = 0; k0 < Lc; k0 += 64) {
    __syncthreads();
    #pragma unroll
    for (int i = 0; i < 4; i++) {
      const int idx = tid + i * 256;
      const int r = idx >> 4, dq = idx & 15;
      const float4 kv = *(const float4*)(K + hb + (size_t)(k0 + r) * Dc + dq * 4);
      const int col = r ^ (dq * 4);
      KP[(dq*4+0)*64 + col] = kv.x;
      KP[(dq*4+1)*64 + col] = kv.y;
      KP[(dq*4+2)*64 + col] = kv.z;
      KP[(dq*4+3)*64 + col] = kv.w;
      *(float4*)&Vs[r * 64 + dq * 4] =
          *(const float4*)(V + hb + (size_t)(k0 + r) * Dc + dq * 4);
    }
    __syncthreads();

    float acc[4][4] = {};
    #pragma unroll 8
    for (int d = 0; d < 64; d++) {
      const int swz = (d >> 2) * 4;
      const float4 a4 = *(const float4*)&Qt[d * 64 + ((ty * 4) ^ swz)];
      const float4 b4 = *(const float4*)&KP[d * 64 + ((tx * 4) ^ swz)];
      acc[0][0] += a4.x*b4.x; acc[0][1] += a4.x*b4.y; acc[0][2] += a4.x*b4.z; acc[0][3] += a4.x*b4.w;
      acc[1][0] += a4.y*b4.x; acc[1][1] += a4.y*b4.y; acc[1][2] += a4.y*b4.z; acc[1][3] += a4.y*b4.w;
      acc[2][0] += a4.z*b4.x; acc[2][1] += a4.z*b4.y; acc[2][2] += a4.z*b4.z; acc[2][3] += a4.z*b4.w;
      acc[3][0] += a4.w*b4.x; acc[3][1] += a4.w*b4.y; acc[3][2] += a4.w*b4.z; acc[3][3] += a4.w*b4.w;
    }

    float p[4][4];
    #pragma unroll
    for (int i = 0; i < 4; i++) {
      const float qg = (float)(q0 + ty * 4 + i);
      float sv[4], tmax = -3.0e38f;
      #pragma unroll
      for (int j = 0; j < 4; j++) {
        const float kg = (float)(k0 + tx * 4 + j);
        sv[j] = acc[i][j] * 0.125f + slope * fmaxf(qg - kg, 0.0f);
        tmax = fmaxf(tmax, sv[j]);
      }
      #pragma unroll
      for (int mk = 1; mk < 16; mk <<= 1) tmax = fmaxf(tmax, __shfl_xor(tmax, mk, 64));
      const float mnew = fmaxf(m_i[i], tmax);
      const float alpha = expf(m_i[i] - mnew);
      float rsum = 0.f;
      #pragma unroll
      for (int j = 0; j < 4; j++) { p[i][j] = expf(sv[j] - mnew); rsum += p[i][j]; }
      #pragma unroll
      for (int mk = 1; mk < 16; mk <<= 1) rsum += __shfl_xor(rsum, mk, 64);
      l_i[i] = l_i[i] * alpha + rsum;
      m_i[i] = mnew;
      #pragma unroll
      for (int j = 0; j < 4; j++) acc_o[i][j] *= alpha;
    }

    __syncthreads();
    #pragma unroll
    for (int i = 0; i < 4; i++)
      #pragma unroll
      for (int j = 0; j < 4; j++)
        KP[(tx*4+j)*64 + (((ty*4+i)) ^ (tx*4))] = p[i][j];
    __syncthreads();

    #pragma unroll 8
    for (int kk = 0; kk < 64; kk++) {
      const int swz = (kk >> 2) * 4;
      const float4 a4 = *(const float4*)&KP[kk * 64 + ((ty * 4) ^ swz)];
      const float4 b4 = *(const float4*)&Vs[kk * 64 + tx * 4];
      acc_o[0][0] += a4.x*b4.x; acc_o[0][1] += a4.x*b4.y; acc_o[0][2] += a4.x*b4.z; acc_o[0][3] += a4.x*b4.w;
      acc_o[1][0] += a4.y*b4.x; acc_o[1][1] += a4.y*b4.y; acc_o[1][2] += a4.y*b4.z; acc_o[1][3] += a4.y*b4.w;
      acc_o[2][0] += a4.z*b4.x; acc_o[2][1] += a4.z*b4.y; acc_o[2][2] += a4.z*b4.z; acc_o[2][3] += a4.z*b4.w;
      acc_o[3][0] += a4.w*b4.x; acc_o[3][1] += a4.w*b4.y; acc_o[3][2] += a4.w*b4.z; acc_o[3][3] += a4.w*b4.w;
    }
  }

  #pragma unroll
  for (int i = 0; i < 4; i++) {
    const float inv = 1.0f / l_i[i];
    float4 o = make_float4(acc_o[i][0]*inv, acc_o[i][1]*inv, acc_o[i][2]*inv, acc_o[i][3]*inv);
    *(float4*)(O + hb + (size_t)(q0 + ty * 4 + i) * Dc + tx * 4) = o;
  }
}

// ---------- layernorm variants (one block per row, D=1024, 4 elems/thread) ----
__global__ __launch_bounds__(256)
void ln_plain_kernel(const float* __restrict__ X, const float* __restrict__ g,
                     const float* __restrict__ be, float* __restrict__ OUT)
{
  __shared__ float red4[4];
  const int row = blockIdx.x, tid = threadIdx.x;
  const size_t base = (size_t)row * Dc + tid * 4;
  const float4 xv = *(const float4*)(X + base);
  float s = xv.x + xv.y + xv.z + xv.w;
  s = block_sum(s, red4);
  const float mean = s * (1.0f / Dc);
  const float d0 = xv.x-mean, d1 = xv.y-mean, d2 = xv.z-mean, d3 = xv.w-mean;
  float ss = d0*d0 + d1*d1 + d2*d2 + d3*d3;
  ss = block_sum(ss, red4);
  const float rstd = rsqrtf(ss * (1.0f / Dc) + 1e-5f);
  const int c = tid * 4;
  float4 o;
  o.x = d0*rstd*ldf(g+c+0) + ldf(be+c+0);
  o.y = d1*rstd*ldf(g+c+1) + ldf(be+c+1);
  o.z = d2*rstd*ldf(g+c+2) + ldf(be+c+2);
  o.w = d3*rstd*ldf(g+c+3) + ldf(be+c+3);
  *(float4*)(OUT + base) = o;
}

__global__ __launch_bounds__(256)   // OUT = RES + ln(X)
void ln_resadd_kernel(const float* __restrict__ X, const float* __restrict__ RES,
                      const float* __restrict__ g, const float* __restrict__ be,
                      float* __restrict__ OUT)
{
  __shared__ float red4[4];
  const int row = blockIdx.x, tid = threadIdx.x;
  const size_t base = (size_t)row * Dc + tid * 4;
  const float4 xv = *(const float4*)(X + base);
  float s = xv.x + xv.y + xv.z + xv.w;
  s = block_sum(s, red4);
  const float mean = s * (1.0f / Dc);
  const float d0 = xv.x-mean, d1 = xv.y-mean, d2 = xv.z-mean, d3 = xv.w-mean;
  float ss = d0*d0 + d1*d1 + d2*d2 + d3*d3;
  ss = block_sum(ss, red4);
  const float rstd = rsqrtf(ss * (1.0f / Dc) + 1e-5f);
  const int c = tid * 4;
  const float4 rv = *(const float4*)(RES + base);
  float4 o;
  o.x = rv.x + d0*rstd*ldf(g+c+0) + ldf(be+c+0);
  o.y = rv.y + d1*rstd*ldf(g+c+1) + ldf(be+c+1);
  o.z = rv.z + d2*rstd*ldf(g+c+2) + ldf(be+c+2);
  o.w = rv.w + d3*rstd*ldf(g+c+3) + ldf(be+c+3);
  *(float4*)(OUT + base) = o;
}

__global__ __launch_bounds__(256)   // OUT = ln(X + Y)
void ln_sum_kernel(const float* __restrict__ X, const float* __restrict__ Y,
                   const float* __restrict__ g, const float* __restrict__ be,
                   float* __restrict__ OUT)
{
  __shared__ float red4[4];
  const int row = blockIdx.x, tid = threadIdx.x;
  const size_t base = (size_t)row * Dc + tid * 4;
  const float4 xv = *(const float4*)(X + base);
  const float4 yv = *(const float4*)(Y + base);
  const float x0 = xv.x+yv.x, x1 = xv.y+yv.y, x2 = xv.z+yv.z, x3 = xv.w+yv.w;
  float s = x0 + x1 + x2 + x3;
  s = block_sum(s, red4);
  const float mean = s * (1.0f / Dc);
  const float d0 = x0-mean, d1 = x1-mean, d2 = x2-mean, d3 = x3-mean;
  float ss = d0*d0 + d1*d1 + d2*d2 + d3*d3;
  ss = block_sum(ss, red4);
  const float rstd = rsqrtf(ss * (1.0f / Dc) + 1e-5f);
  const int c = tid * 4;
  float4 o;
  o.x = d0*rstd*ldf(g+c+0) + ldf(be+c+0);
  o.y = d1*rstd*ldf(g+c+1) + ldf(be+c+1);
  o.z = d2*rstd*ldf(g+c+2) + ldf(be+c+2);
  o.w = d3*rstd*ldf(g+c+3) + ldf(be+c+3);
  *(float4*)(OUT + base) = o;
}

// ---------- GLU ----------
__global__ __launch_bounds__(256)
void glu_kernel(const float* __restrict__ H1, float* __restrict__ HG)
{
  const int gid = blockIdx.x * 256 + threadIdx.x;
  const int t = gid >> 8;
  const int c4 = (gid & 255) * 4;
  const float* p = H1 + (size_t)t * (2 * Dc);
  const float4 a = *(const float4*)(p + c4);
  const float4 gg = *(const float4*)(p + Dc + c4);
  float4 o;
  o.x = a.x / (1.0f + expf(-gg.x));
  o.y = a.y / (1.0f + expf(-gg.y));
  o.z = a.z / (1.0f + expf(-gg.z));
  o.w = a.w / (1.0f + expf(-gg.w));
  *(float4*)(HG + (size_t)t * Dc + c4) = o;
}

// ---------- depthwise conv K=5 (+bias, bn-scale, hardswish) ----------
__global__ __launch_bounds__(256)
void dwconv_kernel(const float* __restrict__ HG, const float* __restrict__ w,
                   const float* __restrict__ wb, const float* __restrict__ gn,
                   const float* __restrict__ bb, float* __restrict__ OUT)
{
  const int gid = blockIdx.x * 256 + threadIdx.x;
  const int d = gid & (Dc - 1);
  const int l = (gid >> 10) & (Lc - 1);
  const int b = gid >> 21;
  const size_t rowb = (size_t)b * Lc;
  float acc = ldf(wb + d);
  #pragma unroll
  for (int s = 0; s < 5; s++) {
    const int lp = l + 2 - s;
    if (lp >= 0 && lp < Lc)
      acc += ldf(w + d * 5 + s) * HG[((rowb + lp) << 10) + d];
  }
  const float rs = rsqrtf(1.0f + 1e-5f);
  const float t = acc * rs * ldf(gn + d) + ldf(bb + d);
  OUT[gid] = t * fminf(fmaxf(t + 3.0f, 0.0f), 6.0f) * (1.0f / 6.0f);
}

// =====================================================================
extern "C" void kernel_launch(void* const* d_in, const int* in_sizes, int n_in,
                              void* d_out, int out_size, void* d_ws, size_t ws_size,
                              hipStream_t stream) {
  (void)in_sizes; (void)n_in; (void)out_size; (void)ws_size;
  const float* mem    = (const float*)d_in[0];
  const float* wq     = (const float*)d_in[1];
  const float* bq     = (const float*)d_in[2];
  const float* wk     = (const float*)d_in[3];
  const float* bk     = (const float*)d_in[4];
  const float* wv     = (const float*)d_in[5];
  const float* bv     = (const float*)d_in[6];
  const float* wo     = (const float*)d_in[7];
  const float* bo     = (const float*)d_in[8];
  const float* n1g    = (const float*)d_in[9];
  const float* n1b    = (const float*)d_in[10];
  const float* clng   = (const float*)d_in[11];
  const float* clnb   = (const float*)d_in[12];
  const float* pw1w   = (const float*)d_in[13];
  const float* pw1b   = (const float*)d_in[14];
  const float* dww    = (const float*)d_in[15];
  const float* dwb    = (const float*)d_in[16];
  const float* bng    = (const float*)d_in[17];
  const float* bnb    = (const float*)d_in[18];
  const float* pw2w   = (const float*)d_in[19];
  const float* pw2b   = (const float*)d_in[20];
  const float* projw  = (const float*)d_in[21];
  const float* projb  = (const float*)d_in[22];
  const float* proj2w = (const float*)d_in[23];
  const float* proj2b = (const float*)d_in[24];
  const float* lin1w  = (const float*)d_in[25];
  const float* lin1b  = (const float*)d_in[26];
  const float* lin2w  = (const float*)d_in[27];
  const float* lin2b  = (const float*)d_in[28];
  const float* n3g    = (const float*)d_in[29];
  const float* n3b    = (const float*)d_in[30];
  float* out = (float*)d_out;

  char* base = (char*)d_ws;
  float* qb   = (float*)base;                    // q  -> tgt2
  float* kb   = qb + TD;                         // k  -> mem1
  float* vb   = kb + TD;                         // v  -> hln -> hc -> ffout
  float* ob   = vb + TD;                         // attn out -> hg -> proj
  float* big1 = ob + TD;                         // h1 lo -> mem2
  float* big2 = big1 + TD;                       // h1 hi -> conv_out
  // bf16 region aliased over the old ffb slot (6TD..10TD floats):
  unsigned short* ffbbf = (unsigned short*)(base + 6 * TD * 4);       // NT*FF
  unsigned short* abf   = ffbbf + (size_t)NT * FFc;                   // TD
  unsigned short* m1T   = abf + TD;                                   // TD
  // bf16 weights after the fp32 region (10TD floats):
  unsigned short* wt = (unsigned short*)(base + 10 * TD * 4);
  unsigned short* wqT    = wt;            // [1024][1024]
  unsigned short* wkT    = wqT + MEG;
  unsigned short* wvT    = wkT + MEG;
  unsigned short* woT    = wvT + MEG;
  unsigned short* pw1T   = woT + MEG;     // [2048][1024]
  unsigned short* pw2T   = pw1T + 2*MEG;  // [1024][1024]
  unsigned short* proj2T = pw2T + MEG;    // [1024][1024]
  unsigned short* projwT = proj2T + MEG;  // [2048][2048]
  unsigned short* lin1T  = projwT + 4*MEG;// [4096][1024]
  unsigned short* lin2T  = lin1T + 4*MEG; // [1024][4096]

  const dim3 blk(256);
  const long long LD = (long long)Lc * Dc;

  // ---- weight transposes (fp32 [R,C] -> bf16 [C,R]) ----
  transpose_convert_kernel<<<dim3(16,16,1),blk,0,stream>>>(wq,    wqT,    1024, 1024, 0, 0);
  transpose_convert_kernel<<<dim3(16,16,1),blk,0,stream>>>(wk,    wkT,    1024, 1024, 0, 0);
  transpose_convert_kernel<<<dim3(16,16,1),blk,0,stream>>>(wv,    wvT,    1024, 1024, 0, 0);
  transpose_convert_kernel<<<dim3(16,16,1),blk,0,stream>>>(wo,    woT,    1024, 1024, 0, 0);
  transpose_convert_kernel<<<dim3(32,16,1),blk,0,stream>>>(pw1w,  pw1T,   1024, 2048, 0, 0);
  transpose_convert_kernel<<<dim3(16,16,1),blk,0,stream>>>(pw2w,  pw2T,   1024, 1024, 0, 0);
  transpose_convert_kernel<<<dim3(16,16,1),blk,0,stream>>>(proj2w,proj2T, 1024, 1024, 0, 0);
  transpose_convert_kernel<<<dim3(32,32,1),blk,0,stream>>>(projw, projwT, 2048, 2048, 0, 0);
  transpose_convert_kernel<<<dim3(64,16,1),blk,0,stream>>>(lin1w, lin1T,  1024, 4096, 0, 0);
  transpose_convert_kernel<<<dim3(16,64,1),blk,0,stream>>>(lin2w, lin2T,  4096, 1024, 0, 0);

  // ---- attention ----
  convert_bf16_kernel<<<dim3((unsigned)(TD/1024)),blk,0,stream>>>(mem, abf);
  mfma_gemm_kernel<EPI_BIAS,false><<<dim3(8,32,1),blk,0,stream>>>(abf,wqT,bq,nullptr,qb,nullptr,NT,Dc,Dc,0,0,0);
  mfma_gemm_kernel<EPI_BIAS,false><<<dim3(8,32,1),blk,0,stream>>>(abf,wkT,bk,nullptr,kb,nullptr,NT,Dc,Dc,0,0,0);
  mfma_gemm_kernel<EPI_BIAS,false><<<dim3(8,32,1),blk,0,stream>>>(abf,wvT,bv,nullptr,vb,nullptr,NT,Dc,Dc,0,0,0);
  rope_kernel<<<dim3(NT*Hc/256),blk,0,stream>>>(qb);
  rope_kernel<<<dim3(NT*Hc/256),blk,0,stream>>>(kb);
  flash_attn_kernel<<<dim3(Lc/64, Bc*Hc),blk,0,stream>>>(qb,kb,vb,ob);
  convert_bf16_kernel<<<dim3((unsigned)(TD/1024)),blk,0,stream>>>(ob, abf);
  mfma_gemm_kernel<EPI_BIAS,false><<<dim3(8,32,1),blk,0,stream>>>(abf,woT,bo,nullptr,qb,nullptr,NT,Dc,Dc,0,0,0);
  ln_resadd_kernel<<<dim3(NT),blk,0,stream>>>(qb, mem, n1g, n1b, kb);   // mem1 -> kb

  // ---- conv block ----
  ln_plain_kernel<<<dim3(NT),blk,0,stream>>>(kb, clng, clnb, vb);       // hln -> vb
  convert_bf16_kernel<<<dim3((unsigned)(TD/1024)),blk,0,stream>>>(vb, abf);
  mfma_gemm_kernel<EPI_BIAS,false><<<dim3(16,32,1),blk,0,stream>>>(abf,pw1T,pw1b,nullptr,big1,nullptr,NT,2*Dc,Dc,0,0,0);
  glu_kernel<<<dim3((unsigned)(TD/4/256)),blk,0,stream>>>(big1, ob);    // hg -> ob
  dwconv_kernel<<<dim3((unsigned)(TD/256)),blk,0,stream>>>(ob, dww, dwb, bng, bnb, vb);  // hc -> vb
  convert_bf16_kernel<<<dim3((unsigned)(TD/1024)),blk,0,stream>>>(vb, abf);
  mfma_gemm_kernel<EPI_ADDROW0,false><<<dim3(8,32,1),blk,0,stream>>>(abf,pw2T,pw2b,kb,big2,nullptr,NT,Dc,Dc,0,0,0);

  // ---- proj path ----
  transpose_convert_kernel<<<dim3(16,32,2),blk,0,stream>>>(kb, m1T, 2048, 1024, LD, LD); // mem1^T per batch
  mfma_gemm_kernel<EPI_BIAS_ROW,false><<<dim3(8,16,2),blk,0,stream>>>(projwT,m1T,projb,nullptr,ob,nullptr,Lc,Dc,Lc,0,LD,LD);
  convert_bf16_kernel<<<dim3((unsigned)(TD/1024)),blk,0,stream>>>(ob, abf);
  mfma_gemm_kernel<EPI_ADD,false><<<dim3(8,32,1),blk,0,stream>>>(abf,proj2T,proj2b,big2,big1,nullptr,NT,Dc,Dc,0,0,0);

  // ---- feed-forward ----
  convert_bf16_kernel<<<dim3((unsigned)(TD/1024)),blk,0,stream>>>(big1, abf);
  mfma_gemm_kernel<EPI_GELU,true><<<dim3(32,32,1),blk,0,stream>>>(abf,lin1T,lin1b,nullptr,nullptr,ffbbf,NT,FFc,Dc,0,0,0);
  mfma_gemm_kernel<EPI_BIAS,false><<<dim3(8,32,1),blk,0,stream>>>(ffbbf,lin2T,lin2b,nullptr,vb,nullptr,NT,Dc,FFc,0,0,0);

  // ---- final: out = ln(mem2 + ffout) ----
  ln_sum_kernel<<<dim3(NT),blk,0,stream>>>(big1, vb, n3g, n3b, out);
}

// Round 5
// 1092.275 us; speedup vs baseline: 10.0578x; 1.3124x over previous
//
#include <hip/hip_runtime.h>
#include <hip/hip_bf16.h>
#include <math.h>

typedef unsigned short ushort_t;

constexpr int Bc = 2, Lc = 2048, Dc = 1024, Hc = 16, HDc = 64, FFc = 4096;
constexpr int NT = Bc * Lc;              // 4096 tokens
constexpr size_t TD = (size_t)NT * Dc;   // 4194304 elements per [B,L,D] tensor
constexpr size_t MEG = 1024 * 1024;

__device__ __forceinline__ float ldf(const float* p) { return *p; }
__device__ __forceinline__ unsigned short f2b(float f) {
  __hip_bfloat16 h = __float2bfloat16(f);
  return *reinterpret_cast<unsigned short*>(&h);
}

using frag   = __attribute__((ext_vector_type(8))) short;   // 8 bf16 (4 VGPRs)
using f32x4v = __attribute__((ext_vector_type(4))) float;   // MFMA C/D

// ---------- block reductions (blockDim.x == 256 = 4 waves) ----------
__device__ __forceinline__ float block_sum(float v, float* red) {
  const int lane = threadIdx.x & 63, w = threadIdx.x >> 6;
  #pragma unroll
  for (int o = 32; o > 0; o >>= 1) v += __shfl_down(v, o, 64);
  __syncthreads();
  if (lane == 0) red[w] = v;
  __syncthreads();
  return red[0] + red[1] + red[2] + red[3];
}

// ---------- fp32 -> bf16 convert (same layout) ----------
__global__ __launch_bounds__(256)
void convert_bf16_kernel(const float* __restrict__ IN, unsigned short* __restrict__ OUT)
{
  const size_t gid = (size_t)blockIdx.x * 256 + threadIdx.x;
  const float4 v = *(const float4*)(IN + gid * 4);
  ushort4 o;
  o.x = f2b(v.x); o.y = f2b(v.y); o.z = f2b(v.z); o.w = f2b(v.w);
  *(ushort4*)(OUT + gid * 4) = o;
}

// ---------- fp32 [R,C] -> bf16 [C,R] transpose-convert ----------
__global__ __launch_bounds__(256)
void transpose_convert_kernel(const float* __restrict__ IN, unsigned short* __restrict__ OUT,
                              int R, int C, long long sIn, long long sOut)
{
  __shared__ float tile[64][65];
  const int t = threadIdx.x;
  const float* in = IN + (long long)blockIdx.z * sIn;
  unsigned short* out = OUT + (long long)blockIdx.z * sOut;
  const int r0 = blockIdx.y * 64, c0 = blockIdx.x * 64;
  #pragma unroll
  for (int i = 0; i < 4; i++) {
    const int r = (t >> 4) + i * 16, c4 = (t & 15) * 4;
    const float4 v = *(const float4*)(in + (size_t)(r0 + r) * C + c0 + c4);
    tile[r][c4+0] = v.x; tile[r][c4+1] = v.y; tile[r][c4+2] = v.z; tile[r][c4+3] = v.w;
  }
  __syncthreads();
  #pragma unroll
  for (int i = 0; i < 4; i++) {
    const int cc = (t >> 4) + i * 16, rr4 = (t & 15) * 4;
    ushort4 o;
    o.x = f2b(tile[rr4+0][cc]); o.y = f2b(tile[rr4+1][cc]);
    o.z = f2b(tile[rr4+2][cc]); o.w = f2b(tile[rr4+3][cc]);
    *(ushort4*)(out + (size_t)(c0 + cc) * R + r0 + rr4) = o;
  }
}

// ---------- MFMA bf16 GEMM: C[m,n] = sum_k A[m,k] * Bt[n,k] (+epilogue) ----
constexpr int EPI_BIAS = 0, EPI_BIAS_ROW = 1, EPI_GELU = 2, EPI_ADD = 3, EPI_ADDROW0 = 4;

template<int EPI, bool OUTBF>
__global__ __launch_bounds__(256)
void mfma_gemm_kernel(const unsigned short* __restrict__ A, const unsigned short* __restrict__ Bt,
                      const float* __restrict__ bias, const float* __restrict__ extra,
                      float* __restrict__ C, unsigned short* __restrict__ Cbf,
                      int M, int N, int K,
                      long long sA, long long sB, long long sC)
{
  __shared__ unsigned short As[4][128][8];
  __shared__ unsigned short Bs[4][128][8];
  const int tid = threadIdx.x;
  const int l = tid & 63, w = tid >> 6;
  const int wm = (w & 1) * 64, wn = (w >> 1) * 64;
  const int m0 = blockIdx.y * 128, n0 = blockIdx.x * 128;
  const unsigned short* Ap = A + (long long)blockIdx.z * sA;
  const unsigned short* Bp = Bt + (long long)blockIdx.z * sB;

  f32x4v acc[4][4];
  #pragma unroll
  for (int mt = 0; mt < 4; mt++)
    #pragma unroll
    for (int nt = 0; nt < 4; nt++) acc[mt][nt] = {0.f, 0.f, 0.f, 0.f};

  const int gr = tid >> 2, gc = tid & 3;
  const int c_ = l >> 4, rm = l & 15;

  for (int k0 = 0; k0 < K; k0 += 32) {
    __syncthreads();
    const uint4 va0 = *(const uint4*)(Ap + (size_t)(m0 + gr)      * K + k0 + gc * 8);
    const uint4 va1 = *(const uint4*)(Ap + (size_t)(m0 + gr + 64) * K + k0 + gc * 8);
    const uint4 vb0 = *(const uint4*)(Bp + (size_t)(n0 + gr)      * K + k0 + gc * 8);
    const uint4 vb1 = *(const uint4*)(Bp + (size_t)(n0 + gr + 64) * K + k0 + gc * 8);
    *(uint4*)&As[gc][gr][0]      = va0;
    *(uint4*)&As[gc][gr + 64][0] = va1;
    *(uint4*)&Bs[gc][gr][0]      = vb0;
    *(uint4*)&Bs[gc][gr + 64][0] = vb1;
    __syncthreads();

    frag af[4], bfr[4];
    #pragma unroll
    for (int mt = 0; mt < 4; mt++) af[mt]  = *(const frag*)&As[c_][wm + mt * 16 + rm][0];
    #pragma unroll
    for (int nt = 0; nt < 4; nt++) bfr[nt] = *(const frag*)&Bs[c_][wn + nt * 16 + rm][0];
    #pragma unroll
    for (int mt = 0; mt < 4; mt++)
      #pragma unroll
      for (int nt = 0; nt < 4; nt++)
        acc[mt][nt] = __builtin_amdgcn_mfma_f32_16x16x32_bf16(af[mt], bfr[nt], acc[mt][nt], 0, 0, 0);
  }

  float* Cp = C + (long long)blockIdx.z * sC;
  unsigned short* Cbp = Cbf + (long long)blockIdx.z * sC;
  #pragma unroll
  for (int mt = 0; mt < 4; mt++) {
    #pragma unroll
    for (int nt = 0; nt < 4; nt++) {
      #pragma unroll
      for (int i = 0; i < 4; i++) {
        const int m = m0 + wm + mt * 16 + c_ * 4 + i;   // C/D: row=(lane>>4)*4+reg
        const int n = n0 + wn + nt * 16 + rm;           //      col=lane&15
        float r = acc[mt][nt][i];
        if constexpr (EPI == EPI_BIAS || EPI == EPI_GELU || EPI == EPI_ADD || EPI == EPI_ADDROW0)
          r += ldf(bias + n);
        if constexpr (EPI == EPI_BIAS_ROW) r += ldf(bias + m);
        if constexpr (EPI == EPI_GELU)
          r = 0.5f * r * (1.0f + erff(r * 0.70710678118654752f));
        if constexpr (EPI == EPI_ADD) r += extra[(size_t)m * N + n];
        if constexpr (EPI == EPI_ADDROW0) r += extra[(size_t)(m >> 11) * ((size_t)Lc * Dc) + n];
        if constexpr (OUTBF) Cbp[(size_t)m * N + n] = f2b(r);
        else                 Cp[(size_t)m * N + n] = r;
      }
    }
  }
}

// ---------- RoPE: read fp32, write bf16 (reference's even/odd -> concat) ----
__global__ __launch_bounds__(256)
void rope_bf16_kernel(const float* __restrict__ X, unsigned short* __restrict__ OUT)
{
  const int gid = blockIdx.x * 256 + threadIdx.x;  // one thread = one (token, head)
  if (gid >= NT * Hc) return;
  const int h = gid & (Hc - 1);
  const int token = gid >> 4;
  const int l = token & (Lc - 1);
  const float* p = X + (size_t)token * Dc + h * HDc;
  unsigned short* po = OUT + (size_t)token * Dc + h * HDc;
  float x[64], out[64];
  #pragma unroll
  for (int i = 0; i < 16; i++) *(float4*)&x[4*i] = *(const float4*)&p[4*i];
  const float lf = (float)l;
  #pragma unroll
  for (int i = 0; i < 32; i++) {
    const int j = (i < 16) ? (2 * i) : (2 * (i - 16));
    const float a0 = lf * powf(10000.0f, -(float)j       / 32.0f);
    const float a1 = lf * powf(10000.0f, -(float)(j + 1) / 32.0f);
    float c, s;
    if (i < 16) { c = cosf(a0); s = cosf(a1); }
    else        { c = sinf(a0); s = sinf(a1); }
    out[i]      = x[2*i] * c - x[2*i+1] * s;
    out[32 + i] = x[2*i] * s + x[2*i+1] * c;
  }
  #pragma unroll
  for (int i = 0; i < 16; i++) {
    ushort4 o;
    o.x = f2b(out[4*i+0]); o.y = f2b(out[4*i+1]);
    o.z = f2b(out[4*i+2]); o.w = f2b(out[4*i+3]);
    *(ushort4*)&po[4*i] = o;
  }
}

// ---------- MFMA flash attention ----------
// One block per (64-q-tile, b*H+h). 4 waves, each owns 16 q-rows.
// Q/K in LDS as [d-granule][row][8 bf16] (natural rows, MFMA A/B frag layout).
// V transposed at staging -> Vt[k-granule][d][8]. P (bf16) -> Ps[k-granule][q][8],
// wave-private rows so no extra barrier. S/O accumulate fp32 via 16x16x32 MFMA.
__global__ __launch_bounds__(256)
void flash_attn_mfma_kernel(const unsigned short* __restrict__ Q,
                            const unsigned short* __restrict__ K,
                            const unsigned short* __restrict__ V,
                            unsigned short* __restrict__ O)
{
  __shared__ unsigned short Qs[8][64][8];
  __shared__ unsigned short Ks[8][64][8];
  __shared__ unsigned short Vt[8][64][8];
  __shared__ unsigned short Ps[8][64][8];
  const int tid = threadIdx.x;
  const int l = tid & 63, w = tid >> 6;
  const int qw = w * 16;
  const int lg = l >> 4, lm = l & 15;
  const int q0 = blockIdx.x * 64;
  const int bh = blockIdx.y;
  const int b = bh >> 4, h = bh & 15;
  const size_t rowbase = (size_t)b * Lc;
  const int dbase = h * 64;
  const float slope = exp2f(-0.5f * (float)h);

  // stage Q once (rows q0..q0+63, head slice)
  #pragma unroll
  for (int i = 0; i < 2; i++) {
    const int id = tid + i * 256;
    const int r = id & 63, g = id >> 6;
    *(uint4*)&Qs[g][r][0] = *(const uint4*)(Q + (rowbase + q0 + r) * Dc + dbase + g * 8);
  }
  __syncthreads();
  frag aq0 = *(const frag*)&Qs[lg][qw + lm][0];
  frag aq1 = *(const frag*)&Qs[4 + lg][qw + lm][0];

  float m_i[4], l_i[4];
  f32x4v acc_o[4];
  #pragma unroll
  for (int i = 0; i < 4; i++) { m_i[i] = -3.0e38f; l_i[i] = 0.f; }
  #pragma unroll
  for (int nt = 0; nt < 4; nt++) acc_o[nt] = {0.f, 0.f, 0.f, 0.f};

  for (int k0 = 0; k0 < Lc; k0 += 64) {
    __syncthreads();   // prior tile's Ks/Vt reads complete
    #pragma unroll
    for (int i = 0; i < 2; i++) {
      const int id = tid + i * 256;
      const int r = id & 63, g = id >> 6;
      *(uint4*)&Ks[g][r][0] = *(const uint4*)(K + (rowbase + k0 + r) * Dc + dbase + g * 8);
      const uint4 vv = *(const uint4*)(V + (rowbase + k0 + r) * Dc + dbase + g * 8);
      alignas(16) unsigned short tmp[8];
      *(uint4*)tmp = vv;
      #pragma unroll
      for (int t = 0; t < 8; t++) Vt[r >> 3][g * 8 + t][r & 7] = tmp[t];
    }
    __syncthreads();

    // ---- S = Q K^T for this wave's 16 q-rows x 64 k ----
    f32x4v acc_s[4];
    #pragma unroll
    for (int nt = 0; nt < 4; nt++) acc_s[nt] = {0.f, 0.f, 0.f, 0.f};
    #pragma unroll
    for (int nt = 0; nt < 4; nt++) {
      frag bk0 = *(const frag*)&Ks[lg][nt * 16 + lm][0];
      acc_s[nt] = __builtin_amdgcn_mfma_f32_16x16x32_bf16(aq0, bk0, acc_s[nt], 0, 0, 0);
      frag bk1 = *(const frag*)&Ks[4 + lg][nt * 16 + lm][0];
      acc_s[nt] = __builtin_amdgcn_mfma_f32_16x16x32_bf16(aq1, bk1, acc_s[nt], 0, 0, 0);
    }

    // ---- online softmax per q-row (C/D layout: row = lg*4+i, col = lm) ----
    #pragma unroll
    for (int i = 0; i < 4; i++) {
      const float qg = (float)(q0 + qw + lg * 4 + i);
      float sv[4], tmax = -3.0e38f;
      #pragma unroll
      for (int nt = 0; nt < 4; nt++) {
        const float kg = (float)(k0 + nt * 16 + lm);
        sv[nt] = acc_s[nt][i] * 0.125f + slope * fmaxf(qg - kg, 0.0f);
        tmax = fmaxf(tmax, sv[nt]);
      }
      #pragma unroll
      for (int mk = 1; mk < 16; mk <<= 1) tmax = fmaxf(tmax, __shfl_xor(tmax, mk, 64));
      const float mnew = fmaxf(m_i[i], tmax);
      const float alpha = expf(m_i[i] - mnew);
      float pv[4], rsum = 0.f;
      #pragma unroll
      for (int nt = 0; nt < 4; nt++) { pv[nt] = expf(sv[nt] - mnew); rsum += pv[nt]; }
      #pragma unroll
      for (int mk = 1; mk < 16; mk <<= 1) rsum += __shfl_xor(rsum, mk, 64);
      l_i[i] = l_i[i] * alpha + rsum;
      m_i[i] = mnew;
      #pragma unroll
      for (int nt = 0; nt < 4; nt++) acc_o[nt][i] *= alpha;
      const int qrow = qw + lg * 4 + i;
      #pragma unroll
      for (int nt = 0; nt < 4; nt++) {
        const int kc = nt * 16 + lm;
        Ps[kc >> 3][qrow][kc & 7] = f2b(pv[nt]);
      }
    }

    // ---- O += P V (Ps rows are wave-private; same-wave LDS order suffices) ----
    frag ap0 = *(const frag*)&Ps[lg][qw + lm][0];
    frag ap1 = *(const frag*)&Ps[4 + lg][qw + lm][0];
    #pragma unroll
    for (int nt = 0; nt < 4; nt++) {
      frag bv0 = *(const frag*)&Vt[lg][nt * 16 + lm][0];
      acc_o[nt] = __builtin_amdgcn_mfma_f32_16x16x32_bf16(ap0, bv0, acc_o[nt], 0, 0, 0);
      frag bv1 = *(const frag*)&Vt[4 + lg][nt * 16 + lm][0];
      acc_o[nt] = __builtin_amdgcn_mfma_f32_16x16x32_bf16(ap1, bv1, acc_o[nt], 0, 0, 0);
    }
  }

  #pragma unroll
  for (int i = 0; i < 4; i++) {
    const float inv = 1.0f / l_i[i];
    const size_t row = rowbase + q0 + qw + lg * 4 + i;
    #pragma unroll
    for (int nt = 0; nt < 4; nt++)
      O[row * Dc + dbase + nt * 16 + lm] = f2b(acc_o[nt][i] * inv);
  }
}

// ---------- layernorm variants ----------
__global__ __launch_bounds__(256)   // bf16 out (feeds MFMA GEMM)
void ln_plain_bf16_kernel(const float* __restrict__ X, const float* __restrict__ g,
                          const float* __restrict__ be, unsigned short* __restrict__ OUT)
{
  __shared__ float red4[4];
  const int row = blockIdx.x, tid = threadIdx.x;
  const size_t base = (size_t)row * Dc + tid * 4;
  const float4 xv = *(const float4*)(X + base);
  float s = xv.x + xv.y + xv.z + xv.w;
  s = block_sum(s, red4);
  const float mean = s * (1.0f / Dc);
  const float d0 = xv.x-mean, d1 = xv.y-mean, d2 = xv.z-mean, d3 = xv.w-mean;
  float ss = d0*d0 + d1*d1 + d2*d2 + d3*d3;
  ss = block_sum(ss, red4);
  const float rstd = rsqrtf(ss * (1.0f / Dc) + 1e-5f);
  const int c = tid * 4;
  ushort4 o;
  o.x = f2b(d0*rstd*ldf(g+c+0) + ldf(be+c+0));
  o.y = f2b(d1*rstd*ldf(g+c+1) + ldf(be+c+1));
  o.z = f2b(d2*rstd*ldf(g+c+2) + ldf(be+c+2));
  o.w = f2b(d3*rstd*ldf(g+c+3) + ldf(be+c+3));
  *(ushort4*)(OUT + base) = o;
}

__global__ __launch_bounds__(256)   // OUT = RES + ln(X)
void ln_resadd_kernel(const float* __restrict__ X, const float* __restrict__ RES,
                      const float* __restrict__ g, const float* __restrict__ be,
                      float* __restrict__ OUT)
{
  __shared__ float red4[4];
  const int row = blockIdx.x, tid = threadIdx.x;
  const size_t base = (size_t)row * Dc + tid * 4;
  const float4 xv = *(const float4*)(X + base);
  float s = xv.x + xv.y + xv.z + xv.w;
  s = block_sum(s, red4);
  const float mean = s * (1.0f / Dc);
  const float d0 = xv.x-mean, d1 = xv.y-mean, d2 = xv.z-mean, d3 = xv.w-mean;
  float ss = d0*d0 + d1*d1 + d2*d2 + d3*d3;
  ss = block_sum(ss, red4);
  const float rstd = rsqrtf(ss * (1.0f / Dc) + 1e-5f);
  const int c = tid * 4;
  const float4 rv = *(const float4*)(RES + base);
  float4 o;
  o.x = rv.x + d0*rstd*ldf(g+c+0) + ldf(be+c+0);
  o.y = rv.y + d1*rstd*ldf(g+c+1) + ldf(be+c+1);
  o.z = rv.z + d2*rstd*ldf(g+c+2) + ldf(be+c+2);
  o.w = rv.w + d3*rstd*ldf(g+c+3) + ldf(be+c+3);
  *(float4*)(OUT + base) = o;
}

__global__ __launch_bounds__(256)   // OUT = ln(X + Y)
void ln_sum_kernel(const float* __restrict__ X, const float* __restrict__ Y,
                   const float* __restrict__ g, const float* __restrict__ be,
                   float* __restrict__ OUT)
{
  __shared__ float red4[4];
  const int row = blockIdx.x, tid = threadIdx.x;
  const size_t base = (size_t)row * Dc + tid * 4;
  const float4 xv = *(const float4*)(X + base);
  const float4 yv = *(const float4*)(Y + base);
  const float x0 = xv.x+yv.x, x1 = xv.y+yv.y, x2 = xv.z+yv.z, x3 = xv.w+yv.w;
  float s = x0 + x1 + x2 + x3;
  s = block_sum(s, red4);
  const float mean = s * (1.0f / Dc);
  const float d0 = x0-mean, d1 = x1-mean, d2 = x2-mean, d3 = x3-mean;
  float ss = d0*d0 + d1*d1 + d2*d2 + d3*d3;
  ss = block_sum(ss, red4);
  const float rstd = rsqrtf(ss * (1.0f / Dc) + 1e-5f);
  const int c = tid * 4;
  float4 o;
  o.x = d0*rstd*ldf(g+c+0) + ldf(be+c+0);
  o.y = d1*rstd*ldf(g+c+1) + ldf(be+c+1);
  o.z = d2*rstd*ldf(g+c+2) + ldf(be+c+2);
  o.w = d3*rstd*ldf(g+c+3) + ldf(be+c+3);
  *(float4*)(OUT + base) = o;
}

// ---------- GLU ----------
__global__ __launch_bounds__(256)
void glu_kernel(const float* __restrict__ H1, float* __restrict__ HG)
{
  const int gid = blockIdx.x * 256 + threadIdx.x;
  const int t = gid >> 8;
  const int c4 = (gid & 255) * 4;
  const float* p = H1 + (size_t)t * (2 * Dc);
  const float4 a = *(const float4*)(p + c4);
  const float4 gg = *(const float4*)(p + Dc + c4);
  float4 o;
  o.x = a.x / (1.0f + expf(-gg.x));
  o.y = a.y / (1.0f + expf(-gg.y));
  o.z = a.z / (1.0f + expf(-gg.z));
  o.w = a.w / (1.0f + expf(-gg.w));
  *(float4*)(HG + (size_t)t * Dc + c4) = o;
}

// ---------- depthwise conv K=5 (+bias, bn-scale, hardswish), bf16 out ----------
__global__ __launch_bounds__(256)
void dwconv_bf16_kernel(const float* __restrict__ HG, const float* __restrict__ w,
                        const float* __restrict__ wb, const float* __restrict__ gn,
                        const float* __restrict__ bb, unsigned short* __restrict__ OUT)
{
  const int gid = blockIdx.x * 256 + threadIdx.x;
  const int d = gid & (Dc - 1);
  const int l = (gid >> 10) & (Lc - 1);
  const int b = gid >> 21;
  const size_t rowb = (size_t)b * Lc;
  float acc = ldf(wb + d);
  #pragma unroll
  for (int s = 0; s < 5; s++) {
    const int lp = l + 2 - s;
    if (lp >= 0 && lp < Lc)
      acc += ldf(w + d * 5 + s) * HG[((rowb + lp) << 10) + d];
  }
  const float rs = rsqrtf(1.0f + 1e-5f);
  const float t = acc * rs * ldf(gn + d) + ldf(bb + d);
  OUT[gid] = f2b(t * fminf(fmaxf(t + 3.0f, 0.0f), 6.0f) * (1.0f / 6.0f));
}

// =====================================================================
extern "C" void kernel_launch(void* const* d_in, const int* in_sizes, int n_in,
                              void* d_out, int out_size, void* d_ws, size_t ws_size,
                              hipStream_t stream) {
  (void)in_sizes; (void)n_in; (void)out_size; (void)ws_size;
  const float* mem    = (const float*)d_in[0];
  const float* wq     = (const float*)d_in[1];
  const float* bq     = (const float*)d_in[2];
  const float* wk     = (const float*)d_in[3];
  const float* bk     = (const float*)d_in[4];
  const float* wv     = (const float*)d_in[5];
  const float* bv     = (const float*)d_in[6];
  const float* wo     = (const float*)d_in[7];
  const float* bo     = (const float*)d_in[8];
  const float* n1g    = (const float*)d_in[9];
  const float* n1b    = (const float*)d_in[10];
  const float* clng   = (const float*)d_in[11];
  const float* clnb   = (const float*)d_in[12];
  const float* pw1w   = (const float*)d_in[13];
  const float* pw1b   = (const float*)d_in[14];
  const float* dww    = (const float*)d_in[15];
  const float* dwb    = (const float*)d_in[16];
  const float* bng    = (const float*)d_in[17];
  const float* bnb    = (const float*)d_in[18];
  const float* pw2w   = (const float*)d_in[19];
  const float* pw2b   = (const float*)d_in[20];
  const float* projw  = (const float*)d_in[21];
  const float* projb  = (const float*)d_in[22];
  const float* proj2w = (const float*)d_in[23];
  const float* proj2b = (const float*)d_in[24];
  const float* lin1w  = (const float*)d_in[25];
  const float* lin1b  = (const float*)d_in[26];
  const float* lin2w  = (const float*)d_in[27];
  const float* lin2b  = (const float*)d_in[28];
  const float* n3g    = (const float*)d_in[29];
  const float* n3b    = (const float*)d_in[30];
  float* out = (float*)d_out;

  char* base = (char*)d_ws;
  float* qb   = (float*)base;          // q fp32 -> tgt2 fp32
  float* kb   = qb + TD;               // k fp32 -> mem1
  float* big1 = kb + TD;               // h1 lo -> mem2
  float* big2 = big1 + TD;             // h1 hi -> conv_out
  float* ob   = big2 + TD;             // hg -> ffout
  unsigned short* abf  = (unsigned short*)(base + 5 * TD * 4);  // bf16 activation hub
  unsigned short* qbf  = abf + TD;
  unsigned short* kbf  = qbf + TD;
  unsigned short* vbf  = kbf + TD;
  unsigned short* m1T  = vbf + TD;
  unsigned short* ffbbf= m1T + TD;     // NT*FF = 4*TD shorts
  unsigned short* wt   = ffbbf + 4 * TD;
  unsigned short* wqT    = wt;            // [1024][1024]
  unsigned short* wkT    = wqT + MEG;
  unsigned short* wvT    = wkT + MEG;
  unsigned short* woT    = wvT + MEG;
  unsigned short* pw1T   = woT + MEG;     // [2048][1024]
  unsigned short* pw2T   = pw1T + 2*MEG;  // [1024][1024]
  unsigned short* proj2T = pw2T + MEG;    // [1024][1024]
  unsigned short* projwT = proj2T + MEG;  // [2048][2048]
  unsigned short* lin1T  = projwT + 4*MEG;// [4096][1024]
  unsigned short* lin2T  = lin1T + 4*MEG; // [1024][4096]

  const dim3 blk(256);
  const long long LD = (long long)Lc * Dc;

  // ---- weight transposes ----
  transpose_convert_kernel<<<dim3(16,16,1),blk,0,stream>>>(wq,    wqT,    1024, 1024, 0, 0);
  transpose_convert_kernel<<<dim3(16,16,1),blk,0,stream>>>(wk,    wkT,    1024, 1024, 0, 0);
  transpose_convert_kernel<<<dim3(16,16,1),blk,0,stream>>>(wv,    wvT,    1024, 1024, 0, 0);
  transpose_convert_kernel<<<dim3(16,16,1),blk,0,stream>>>(wo,    woT,    1024, 1024, 0, 0);
  transpose_convert_kernel<<<dim3(32,16,1),blk,0,stream>>>(pw1w,  pw1T,   1024, 2048, 0, 0);
  transpose_convert_kernel<<<dim3(16,16,1),blk,0,stream>>>(pw2w,  pw2T,   1024, 1024, 0, 0);
  transpose_convert_kernel<<<dim3(16,16,1),blk,0,stream>>>(proj2w,proj2T, 1024, 1024, 0, 0);
  transpose_convert_kernel<<<dim3(32,32,1),blk,0,stream>>>(projw, projwT, 2048, 2048, 0, 0);
  transpose_convert_kernel<<<dim3(64,16,1),blk,0,stream>>>(lin1w, lin1T,  1024, 4096, 0, 0);
  transpose_convert_kernel<<<dim3(16,64,1),blk,0,stream>>>(lin2w, lin2T,  4096, 1024, 0, 0);

  // ---- attention ----
  convert_bf16_kernel<<<dim3((unsigned)(TD/1024)),blk,0,stream>>>(mem, abf);
  mfma_gemm_kernel<EPI_BIAS,false><<<dim3(8,32,1),blk,0,stream>>>(abf,wqT,bq,nullptr,qb,nullptr,NT,Dc,Dc,0,0,0);
  mfma_gemm_kernel<EPI_BIAS,false><<<dim3(8,32,1),blk,0,stream>>>(abf,wkT,bk,nullptr,kb,nullptr,NT,Dc,Dc,0,0,0);
  mfma_gemm_kernel<EPI_BIAS,true ><<<dim3(8,32,1),blk,0,stream>>>(abf,wvT,bv,nullptr,nullptr,vbf,NT,Dc,Dc,0,0,0);
  rope_bf16_kernel<<<dim3(NT*Hc/256),blk,0,stream>>>(qb, qbf);
  rope_bf16_kernel<<<dim3(NT*Hc/256),blk,0,stream>>>(kb, kbf);
  flash_attn_mfma_kernel<<<dim3(Lc/64, Bc*Hc),blk,0,stream>>>(qbf,kbf,vbf,abf);
  mfma_gemm_kernel<EPI_BIAS,false><<<dim3(8,32,1),blk,0,stream>>>(abf,woT,bo,nullptr,qb,nullptr,NT,Dc,Dc,0,0,0);
  ln_resadd_kernel<<<dim3(NT),blk,0,stream>>>(qb, mem, n1g, n1b, kb);   // mem1 -> kb

  // ---- conv block ----
  ln_plain_bf16_kernel<<<dim3(NT),blk,0,stream>>>(kb, clng, clnb, abf);
  mfma_gemm_kernel<EPI_BIAS,false><<<dim3(16,32,1),blk,0,stream>>>(abf,pw1T,pw1b,nullptr,big1,nullptr,NT,2*Dc,Dc,0,0,0);
  glu_kernel<<<dim3((unsigned)(TD/4/256)),blk,0,stream>>>(big1, ob);
  dwconv_bf16_kernel<<<dim3((unsigned)(TD/256)),blk,0,stream>>>(ob, dww, dwb, bng, bnb, abf);
  mfma_gemm_kernel<EPI_ADDROW0,false><<<dim3(8,32,1),blk,0,stream>>>(abf,pw2T,pw2b,kb,big2,nullptr,NT,Dc,Dc,0,0,0);

  // ---- proj path ----
  transpose_convert_kernel<<<dim3(16,32,2),blk,0,stream>>>(kb, m1T, 2048, 1024, LD, LD);
  mfma_gemm_kernel<EPI_BIAS_ROW,true><<<dim3(8,16,2),blk,0,stream>>>(projwT,m1T,projb,nullptr,nullptr,abf,Lc,Dc,Lc,0,LD,LD);
  mfma_gemm_kernel<EPI_ADD,false><<<dim3(8,32,1),blk,0,stream>>>(abf,proj2T,proj2b,big2,big1,nullptr,NT,Dc,Dc,0,0,0);

  // ---- feed-forward ----
  convert_bf16_kernel<<<dim3((unsigned)(TD/1024)),blk,0,stream>>>(big1, abf);
  mfma_gemm_kernel<EPI_GELU,true><<<dim3(32,32,1),blk,0,stream>>>(abf,lin1T,lin1b,nullptr,nullptr,ffbbf,NT,FFc,Dc,0,0,0);
  mfma_gemm_kernel<EPI_BIAS,false><<<dim3(8,32,1),blk,0,stream>>>(ffbbf,lin2T,lin2b,nullptr,ob,nullptr,NT,Dc,FFc,0,0,0);

  // ---- final: out = ln(mem2 + ffout) ----
  ln_sum_kernel<<<dim3(NT),blk,0,stream>>>(big1, ob, n3g, n3b, out);
}

// Round 6
// 888.569 us; speedup vs baseline: 12.3635x; 1.2293x over previous
//
#include <hip/hip_runtime.h>
#include <hip/hip_bf16.h>
#include <math.h>

constexpr int Bc = 2, Lc = 2048, Dc = 1024, Hc = 16, HDc = 64, FFc = 4096;
constexpr int NT = Bc * Lc;              // 4096 tokens
constexpr size_t TD = (size_t)NT * Dc;   // 4194304 elements per [B,L,D] tensor
constexpr size_t MEG = 1024 * 1024;

__device__ __forceinline__ float ldf(const float* p) { return *p; }
__device__ __forceinline__ unsigned short f2b(float f) {
  __hip_bfloat16 h = __float2bfloat16(f);
  return *reinterpret_cast<unsigned short*>(&h);
}

using frag   = __attribute__((ext_vector_type(8))) short;   // 8 bf16 (4 VGPRs)
using f32x4v = __attribute__((ext_vector_type(4))) float;   // MFMA C/D

// ---------- block reductions (blockDim.x == 256 = 4 waves) ----------
__device__ __forceinline__ float block_sum(float v, float* red) {
  const int lane = threadIdx.x & 63, w = threadIdx.x >> 6;
  #pragma unroll
  for (int o = 32; o > 0; o >>= 1) v += __shfl_down(v, o, 64);
  __syncthreads();
  if (lane == 0) red[w] = v;
  __syncthreads();
  return red[0] + red[1] + red[2] + red[3];
}

// ---------- fp32 -> bf16 convert ----------
__global__ __launch_bounds__(256)
void convert_bf16_kernel(const float* __restrict__ IN, unsigned short* __restrict__ OUT)
{
  const size_t gid = (size_t)blockIdx.x * 256 + threadIdx.x;
  const float4 v = *(const float4*)(IN + gid * 4);
  ushort4 o;
  o.x = f2b(v.x); o.y = f2b(v.y); o.z = f2b(v.z); o.w = f2b(v.w);
  *(ushort4*)(OUT + gid * 4) = o;
}

// ---------- fp32 [R,C] -> bf16 [C,R] transpose-convert (z-batched) ----------
__global__ __launch_bounds__(256)
void transpose_convert_kernel(const float* __restrict__ IN, unsigned short* __restrict__ OUT,
                              int R, int C, long long sIn, long long sOut)
{
  __shared__ float tile[64][65];
  const int t = threadIdx.x;
  const float* in = IN + (long long)blockIdx.z * sIn;
  unsigned short* out = OUT + (long long)blockIdx.z * sOut;
  const int r0 = blockIdx.y * 64, c0 = blockIdx.x * 64;
  #pragma unroll
  for (int i = 0; i < 4; i++) {
    const int r = (t >> 4) + i * 16, c4 = (t & 15) * 4;
    const float4 v = *(const float4*)(in + (size_t)(r0 + r) * C + c0 + c4);
    tile[r][c4+0] = v.x; tile[r][c4+1] = v.y; tile[r][c4+2] = v.z; tile[r][c4+3] = v.w;
  }
  __syncthreads();
  #pragma unroll
  for (int i = 0; i < 4; i++) {
    const int cc = (t >> 4) + i * 16, rr4 = (t & 15) * 4;
    ushort4 o;
    o.x = f2b(tile[rr4+0][cc]); o.y = f2b(tile[rr4+1][cc]);
    o.z = f2b(tile[rr4+2][cc]); o.w = f2b(tile[rr4+3][cc]);
    *(ushort4*)(out + (size_t)(c0 + cc) * R + r0 + rr4) = o;
  }
}

// ---------- fused weight transposes: 10 segments in one launch ----------
struct TPack {
  const float* in[10]; unsigned short* out[10];
  int R[10], C[10], tx[10], start[10];
};
__global__ __launch_bounds__(256)
void fused_transpose_kernel(TPack p)
{
  __shared__ float tile[64][65];
  const int bid = blockIdx.x;
  int s = 0;
  #pragma unroll
  for (int i = 1; i < 10; i++) s = (bid >= p.start[i]) ? i : s;
  const float* in = p.in[s];
  unsigned short* out = p.out[s];
  const int R = p.R[s], C = p.C[s];
  const int local = bid - p.start[s];
  const int bx = local % p.tx[s], by = local / p.tx[s];
  const int r0 = by * 64, c0 = bx * 64;
  const int t = threadIdx.x;
  #pragma unroll
  for (int i = 0; i < 4; i++) {
    const int r = (t >> 4) + i * 16, c4 = (t & 15) * 4;
    const float4 v = *(const float4*)(in + (size_t)(r0 + r) * C + c0 + c4);
    tile[r][c4+0] = v.x; tile[r][c4+1] = v.y; tile[r][c4+2] = v.z; tile[r][c4+3] = v.w;
  }
  __syncthreads();
  #pragma unroll
  for (int i = 0; i < 4; i++) {
    const int cc = (t >> 4) + i * 16, rr4 = (t & 15) * 4;
    ushort4 o;
    o.x = f2b(tile[rr4+0][cc]); o.y = f2b(tile[rr4+1][cc]);
    o.z = f2b(tile[rr4+2][cc]); o.w = f2b(tile[rr4+3][cc]);
    *(ushort4*)(out + (size_t)(c0 + cc) * R + r0 + rr4) = o;
  }
}

// ---------- MFMA bf16 GEMM with register prefetch of next K-tile ----------
constexpr int EPI_BIAS = 0, EPI_BIAS_ROW = 1, EPI_GELU = 2, EPI_ADD = 3, EPI_ADDROW0 = 4;

template<int EPI, bool OUTBF>
__global__ __launch_bounds__(256)
void mfma_gemm_kernel(const unsigned short* __restrict__ A, const unsigned short* __restrict__ Bt,
                      const float* __restrict__ bias, const float* __restrict__ extra,
                      float* __restrict__ C, unsigned short* __restrict__ Cbf,
                      int M, int N, int K,
                      long long sA, long long sB, long long sC)
{
  __shared__ unsigned short As[4][128][8];
  __shared__ unsigned short Bs[4][128][8];
  const int tid = threadIdx.x;
  const int l = tid & 63, w = tid >> 6;
  const int wm = (w & 1) * 64, wn = (w >> 1) * 64;
  const int m0 = blockIdx.y * 128, n0 = blockIdx.x * 128;
  const unsigned short* Ap = A + (long long)blockIdx.z * sA;
  const unsigned short* Bp = Bt + (long long)blockIdx.z * sB;

  f32x4v acc[4][4];
  #pragma unroll
  for (int mt = 0; mt < 4; mt++)
    #pragma unroll
    for (int nt = 0; nt < 4; nt++) acc[mt][nt] = {0.f, 0.f, 0.f, 0.f};

  const int gr = tid >> 2, gc = tid & 3;
  const int c_ = l >> 4, rm = l & 15;

  uint4 va0 = *(const uint4*)(Ap + (size_t)(m0 + gr)      * K + gc * 8);
  uint4 va1 = *(const uint4*)(Ap + (size_t)(m0 + gr + 64) * K + gc * 8);
  uint4 vb0 = *(const uint4*)(Bp + (size_t)(n0 + gr)      * K + gc * 8);
  uint4 vb1 = *(const uint4*)(Bp + (size_t)(n0 + gr + 64) * K + gc * 8);

  for (int k0 = 0; k0 < K; k0 += 32) {
    __syncthreads();
    *(uint4*)&As[gc][gr][0]      = va0;
    *(uint4*)&As[gc][gr + 64][0] = va1;
    *(uint4*)&Bs[gc][gr][0]      = vb0;
    *(uint4*)&Bs[gc][gr + 64][0] = vb1;
    __syncthreads();

    const int kn = (k0 + 32 < K) ? (k0 + 32) : 0;   // prefetch next tile (wrap harmless)
    va0 = *(const uint4*)(Ap + (size_t)(m0 + gr)      * K + kn + gc * 8);
    va1 = *(const uint4*)(Ap + (size_t)(m0 + gr + 64) * K + kn + gc * 8);
    vb0 = *(const uint4*)(Bp + (size_t)(n0 + gr)      * K + kn + gc * 8);
    vb1 = *(const uint4*)(Bp + (size_t)(n0 + gr + 64) * K + kn + gc * 8);

    frag af[4], bfr[4];
    #pragma unroll
    for (int mt = 0; mt < 4; mt++) af[mt]  = *(const frag*)&As[c_][wm + mt * 16 + rm][0];
    #pragma unroll
    for (int nt = 0; nt < 4; nt++) bfr[nt] = *(const frag*)&Bs[c_][wn + nt * 16 + rm][0];
    #pragma unroll
    for (int mt = 0; mt < 4; mt++)
      #pragma unroll
      for (int nt = 0; nt < 4; nt++)
        acc[mt][nt] = __builtin_amdgcn_mfma_f32_16x16x32_bf16(af[mt], bfr[nt], acc[mt][nt], 0, 0, 0);
  }

  float* Cp = C + (long long)blockIdx.z * sC;
  unsigned short* Cbp = Cbf + (long long)blockIdx.z * sC;
  #pragma unroll
  for (int mt = 0; mt < 4; mt++) {
    #pragma unroll
    for (int nt = 0; nt < 4; nt++) {
      #pragma unroll
      for (int i = 0; i < 4; i++) {
        const int m = m0 + wm + mt * 16 + c_ * 4 + i;   // C/D: row=(lane>>4)*4+reg
        const int n = n0 + wn + nt * 16 + rm;           //      col=lane&15
        float r = acc[mt][nt][i];
        if constexpr (EPI == EPI_BIAS || EPI == EPI_GELU || EPI == EPI_ADD || EPI == EPI_ADDROW0)
          r += ldf(bias + n);
        if constexpr (EPI == EPI_BIAS_ROW) r += ldf(bias + m);
        if constexpr (EPI == EPI_GELU)
          r = 0.5f * r * (1.0f + erff(r * 0.70710678118654752f));
        if constexpr (EPI == EPI_ADD) r += extra[(size_t)m * N + n];
        if constexpr (EPI == EPI_ADDROW0) r += extra[(size_t)(m >> 11) * ((size_t)Lc * Dc) + n];
        if constexpr (OUTBF) Cbp[(size_t)m * N + n] = f2b(r);
        else                 Cp[(size_t)m * N + n] = r;
      }
    }
  }
}

// ---------- RoPE table fill: pet[l][j] = cos(l*w_j) (j<32), sin (j>=32) ----------
__global__ __launch_bounds__(256)
void pe_fill_kernel(float* __restrict__ pet)
{
  const int gid = blockIdx.x * 256 + threadIdx.x;  // Lc*64
  const int l = gid >> 6, t = gid & 63;
  const int j = t & 31;
  // 10000^(-j/32) = 2^(-j/32 * log2(10000))
  const float wj = exp2f(-(float)j * (13.2877123795494f / 32.0f));
  const float ang = (float)l * wj;
  pet[gid] = (t < 32) ? cosf(ang) : sinf(ang);
}

// ---------- fused RoPE for Q and K: fp32 in, bf16 out ----------
__global__ __launch_bounds__(256)
void rope2_kernel(const float* __restrict__ Qi, const float* __restrict__ Ki,
                  const float* __restrict__ pet,
                  unsigned short* __restrict__ Qo, unsigned short* __restrict__ Ko)
{
  int gid = blockIdx.x * 256 + threadIdx.x;  // 2*NT*Hc
  const int sel = gid >= NT * Hc;
  if (sel) gid -= NT * Hc;
  const float* X = sel ? Ki : Qi;
  unsigned short* O = sel ? Ko : Qo;
  const int h = gid & (Hc - 1);
  const int token = gid >> 4;
  const int l = token & (Lc - 1);
  const float* p = X + (size_t)token * Dc + h * HDc;
  unsigned short* po = O + (size_t)token * Dc + h * HDc;
  const float* pr = pet + l * 64;
  float x[64], out[64];
  #pragma unroll
  for (int i = 0; i < 16; i++) *(float4*)&x[4*i] = *(const float4*)&p[4*i];
  #pragma unroll
  for (int u = 0; u < 32; u++) {
    const int base = (u < 16) ? (2 * u) : (32 + 2 * (u - 16));
    const float c = pr[base], s = pr[base + 1];
    out[u]      = x[2*u] * c - x[2*u+1] * s;
    out[32 + u] = x[2*u] * s + x[2*u+1] * c;
  }
  #pragma unroll
  for (int i = 0; i < 16; i++) {
    ushort4 o;
    o.x = f2b(out[4*i+0]); o.y = f2b(out[4*i+1]);
    o.z = f2b(out[4*i+2]); o.w = f2b(out[4*i+3]);
    *(ushort4*)&po[4*i] = o;
  }
}

// ---------- MFMA flash attention, conflict-free LDS layouts ----------
// Q/K/V^T in LDS as [row][granule ^ (row&7)][8] bf16 (stores lane-contiguous,
// frag reads XOR-spread). P in padded Ps[64][72] (2-way max). Softmax base-2.
// V is consumed from a GLOBAL pre-transposed V^T [b][1024 d][2048 l].
__global__ __launch_bounds__(256)
void flash_attn_mfma_kernel(const unsigned short* __restrict__ Q,
                            const unsigned short* __restrict__ K,
                            const unsigned short* __restrict__ VT,
                            unsigned short* __restrict__ O)
{
  __shared__ unsigned short Qs[64][8][8];
  __shared__ unsigned short Ks[64][8][8];
  __shared__ unsigned short Vt[64][8][8];
  __shared__ unsigned short Ps[64][72];
  const int tid = threadIdx.x;
  const int l = tid & 63, w = tid >> 6;
  const int qw = w * 16;
  const int lg = l >> 4, lm = l & 15;
  const int q0 = blockIdx.x * 64;
  const int bh = blockIdx.y;
  const int b = bh >> 4, h = bh & 15;
  const size_t rowbase = (size_t)b * Lc;
  const size_t vbase = (size_t)b * Lc * Dc;
  const int dbase = h * 64;
  const float sc1 = 0.125f * 1.44269504f;                  // scale * log2(e)
  const float sl2 = exp2f(-0.5f * (float)h) * 1.44269504f; // slope * log2(e)

  // stage Q once
  #pragma unroll
  for (int i = 0; i < 2; i++) {
    const int id = tid + i * 256;
    const int r = id >> 3, g = id & 7;
    *(uint4*)&Qs[r][g ^ (r & 7)][0] =
        *(const uint4*)(Q + (rowbase + q0 + r) * Dc + dbase + g * 8);
  }
  __syncthreads();
  frag aq[2];
  #pragma unroll
  for (int s = 0; s < 2; s++)
    aq[s] = *(const frag*)&Qs[qw + lm][(s * 4 + lg) ^ (lm & 7)][0];

  float m_i[4], l_i[4];
  f32x4v acc_o[4];
  #pragma unroll
  for (int i = 0; i < 4; i++) { m_i[i] = -3.0e38f; l_i[i] = 0.f; }
  #pragma unroll
  for (int nt = 0; nt < 4; nt++) acc_o[nt] = {0.f, 0.f, 0.f, 0.f};

  // prefetch tile 0
  uint4 pk[2], pv4[2];
  #pragma unroll
  for (int i = 0; i < 2; i++) {
    const int id = tid + i * 256;
    const int r = id >> 3, g = id & 7;
    pk[i]  = *(const uint4*)(K  + (rowbase + r) * Dc + dbase + g * 8);
    pv4[i] = *(const uint4*)(VT + vbase + (size_t)(dbase + r) * Lc + g * 8);
  }

  for (int k0 = 0; k0 < Lc; k0 += 64) {
    __syncthreads();   // prior tile's Ks/Vt reads complete
    #pragma unroll
    for (int i = 0; i < 2; i++) {
      const int id = tid + i * 256;
      const int r = id >> 3, g = id & 7;
      *(uint4*)&Ks[r][g ^ (r & 7)][0] = pk[i];
      *(uint4*)&Vt[r][g ^ (r & 7)][0] = pv4[i];
    }
    __syncthreads();

    const int kn = (k0 + 64 < Lc) ? k0 + 64 : 0;   // prefetch next (wrap harmless)
    #pragma unroll
    for (int i = 0; i < 2; i++) {
      const int id = tid + i * 256;
      const int r = id >> 3, g = id & 7;
      pk[i]  = *(const uint4*)(K  + (rowbase + kn + r) * Dc + dbase + g * 8);
      pv4[i] = *(const uint4*)(VT + vbase + (size_t)(dbase + r) * Lc + kn + g * 8);
    }

    // ---- S = Q K^T : wave's 16 q-rows x 64 k ----
    f32x4v acc_s[4];
    #pragma unroll
    for (int nt = 0; nt < 4; nt++) acc_s[nt] = {0.f, 0.f, 0.f, 0.f};
    #pragma unroll
    for (int nt = 0; nt < 4; nt++) {
      #pragma unroll
      for (int s = 0; s < 2; s++) {
        frag bk = *(const frag*)&Ks[nt * 16 + lm][(s * 4 + lg) ^ (lm & 7)][0];
        acc_s[nt] = __builtin_amdgcn_mfma_f32_16x16x32_bf16(aq[s], bk, acc_s[nt], 0, 0, 0);
      }
    }

    // ---- online softmax (base-2) per q-row ----
    #pragma unroll
    for (int i = 0; i < 4; i++) {
      const float qg = (float)(q0 + qw + lg * 4 + i);
      float sv[4], tmax = -3.0e38f;
      #pragma unroll
      for (int nt = 0; nt < 4; nt++) {
        const float kg = (float)(k0 + nt * 16 + lm);
        sv[nt] = acc_s[nt][i] * sc1 + sl2 * fmaxf(qg - kg, 0.0f);
        tmax = fmaxf(tmax, sv[nt]);
      }
      #pragma unroll
      for (int mk = 1; mk < 16; mk <<= 1) tmax = fmaxf(tmax, __shfl_xor(tmax, mk, 64));
      const float mnew = fmaxf(m_i[i], tmax);
      const float alpha = exp2f(m_i[i] - mnew);
      float pv[4], rsum = 0.f;
      #pragma unroll
      for (int nt = 0; nt < 4; nt++) { pv[nt] = exp2f(sv[nt] - mnew); rsum += pv[nt]; }
      #pragma unroll
      for (int mk = 1; mk < 16; mk <<= 1) rsum += __shfl_xor(rsum, mk, 64);
      l_i[i] = l_i[i] * alpha + rsum;
      m_i[i] = mnew;
      #pragma unroll
      for (int nt = 0; nt < 4; nt++) acc_o[nt][i] *= alpha;
      const int qrow = qw + lg * 4 + i;
      #pragma unroll
      for (int nt = 0; nt < 4; nt++) Ps[qrow][nt * 16 + lm] = f2b(pv[nt]);
    }

    // ---- O += P V (Ps rows wave-private; same-wave order suffices) ----
    #pragma unroll
    for (int s = 0; s < 2; s++) {
      frag ap = *(const frag*)&Ps[qw + lm][s * 32 + lg * 8];
      #pragma unroll
      for (int nt = 0; nt < 4; nt++) {
        frag bv = *(const frag*)&Vt[nt * 16 + lm][(s * 4 + lg) ^ (lm & 7)][0];
        acc_o[nt] = __builtin_amdgcn_mfma_f32_16x16x32_bf16(ap, bv, acc_o[nt], 0, 0, 0);
      }
    }
  }

  // epilogue: bounce O through Ps for coalesced global stores
  __syncthreads();
  #pragma unroll
  for (int i = 0; i < 4; i++) {
    const float inv = 1.0f / l_i[i];
    const int qrow = qw + lg * 4 + i;
    #pragma unroll
    for (int nt = 0; nt < 4; nt++)
      Ps[qrow][nt * 16 + lm] = f2b(acc_o[nt][i] * inv);
  }
  __syncthreads();
  #pragma unroll
  for (int i = 0; i < 2; i++) {
    const int id = tid + i * 256;
    const int r = id >> 3, g = id & 7;
    alignas(16) unsigned short tmp[8];
    #pragma unroll
    for (int t = 0; t < 8; t++) tmp[t] = Ps[r][g * 8 + t];
    *(uint4*)(O + (rowbase + q0 + r) * Dc + dbase + g * 8) = *(uint4*)tmp;
  }
}

// ---------- layernorm variants ----------
__global__ __launch_bounds__(256)
void ln_plain_bf16_kernel(const float* __restrict__ X, const float* __restrict__ g,
                          const float* __restrict__ be, unsigned short* __restrict__ OUT)
{
  __shared__ float red4[4];
  const int row = blockIdx.x, tid = threadIdx.x;
  const size_t base = (size_t)row * Dc + tid * 4;
  const float4 xv = *(const float4*)(X + base);
  float s = xv.x + xv.y + xv.z + xv.w;
  s = block_sum(s, red4);
  const float mean = s * (1.0f / Dc);
  const float d0 = xv.x-mean, d1 = xv.y-mean, d2 = xv.z-mean, d3 = xv.w-mean;
  float ss = d0*d0 + d1*d1 + d2*d2 + d3*d3;
  ss = block_sum(ss, red4);
  const float rstd = rsqrtf(ss * (1.0f / Dc) + 1e-5f);
  const int c = tid * 4;
  ushort4 o;
  o.x = f2b(d0*rstd*ldf(g+c+0) + ldf(be+c+0));
  o.y = f2b(d1*rstd*ldf(g+c+1) + ldf(be+c+1));
  o.z = f2b(d2*rstd*ldf(g+c+2) + ldf(be+c+2));
  o.w = f2b(d3*rstd*ldf(g+c+3) + ldf(be+c+3));
  *(ushort4*)(OUT + base) = o;
}

__global__ __launch_bounds__(256)   // OUT = RES + ln(X)
void ln_resadd_kernel(const float* __restrict__ X, const float* __restrict__ RES,
                      const float* __restrict__ g, const float* __restrict__ be,
                      float* __restrict__ OUT)
{
  __shared__ float red4[4];
  const int row = blockIdx.x, tid = threadIdx.x;
  const size_t base = (size_t)row * Dc + tid * 4;
  const float4 xv = *(const float4*)(X + base);
  float s = xv.x + xv.y + xv.z + xv.w;
  s = block_sum(s, red4);
  const float mean = s * (1.0f / Dc);
  const float d0 = xv.x-mean, d1 = xv.y-mean, d2 = xv.z-mean, d3 = xv.w-mean;
  float ss = d0*d0 + d1*d1 + d2*d2 + d3*d3;
  ss = block_sum(ss, red4);
  const float rstd = rsqrtf(ss * (1.0f / Dc) + 1e-5f);
  const int c = tid * 4;
  const float4 rv = *(const float4*)(RES + base);
  float4 o;
  o.x = rv.x + d0*rstd*ldf(g+c+0) + ldf(be+c+0);
  o.y = rv.y + d1*rstd*ldf(g+c+1) + ldf(be+c+1);
  o.z = rv.z + d2*rstd*ldf(g+c+2) + ldf(be+c+2);
  o.w = rv.w + d3*rstd*ldf(g+c+3) + ldf(be+c+3);
  *(float4*)(OUT + base) = o;
}

__global__ __launch_bounds__(256)   // OUT = ln(X + Y)
void ln_sum_kernel(const float* __restrict__ X, const float* __restrict__ Y,
                   const float* __restrict__ g, const float* __restrict__ be,
                   float* __restrict__ OUT)
{
  __shared__ float red4[4];
  const int row = blockIdx.x, tid = threadIdx.x;
  const size_t base = (size_t)row * Dc + tid * 4;
  const float4 xv = *(const float4*)(X + base);
  const float4 yv = *(const float4*)(Y + base);
  const float x0 = xv.x+yv.x, x1 = xv.y+yv.y, x2 = xv.z+yv.z, x3 = xv.w+yv.w;
  float s = x0 + x1 + x2 + x3;
  s = block_sum(s, red4);
  const float mean = s * (1.0f / Dc);
  const float d0 = x0-mean, d1 = x1-mean, d2 = x2-mean, d3 = x3-mean;
  float ss = d0*d0 + d1*d1 + d2*d2 + d3*d3;
  ss = block_sum(ss, red4);
  const float rstd = rsqrtf(ss * (1.0f / Dc) + 1e-5f);
  const int c = tid * 4;
  float4 o;
  o.x = d0*rstd*ldf(g+c+0) + ldf(be+c+0);
  o.y = d1*rstd*ldf(g+c+1) + ldf(be+c+1);
  o.z = d2*rstd*ldf(g+c+2) + ldf(be+c+2);
  o.w = d3*rstd*ldf(g+c+3) + ldf(be+c+3);
  *(float4*)(OUT + base) = o;
}

// ---------- GLU ----------
__global__ __launch_bounds__(256)
void glu_kernel(const float* __restrict__ H1, float* __restrict__ HG)
{
  const int gid = blockIdx.x * 256 + threadIdx.x;
  const int t = gid >> 8;
  const int c4 = (gid & 255) * 4;
  const float* p = H1 + (size_t)t * (2 * Dc);
  const float4 a = *(const float4*)(p + c4);
  const float4 gg = *(const float4*)(p + Dc + c4);
  float4 o;
  o.x = a.x / (1.0f + expf(-gg.x));
  o.y = a.y / (1.0f + expf(-gg.y));
  o.z = a.z / (1.0f + expf(-gg.z));
  o.w = a.w / (1.0f + expf(-gg.w));
  *(float4*)(HG + (size_t)t * Dc + c4) = o;
}

// ---------- depthwise conv K=5 (+bias, bn-scale, hardswish), bf16 out ----------
__global__ __launch_bounds__(256)
void dwconv_bf16_kernel(const float* __restrict__ HG, const float* __restrict__ w,
                        const float* __restrict__ wb, const float* __restrict__ gn,
                        const float* __restrict__ bb, unsigned short* __restrict__ OUT)
{
  const int gid = blockIdx.x * 256 + threadIdx.x;
  const int d = gid & (Dc - 1);
  const int l = (gid >> 10) & (Lc - 1);
  const int b = gid >> 21;
  const size_t rowb = (size_t)b * Lc;
  float acc = ldf(wb + d);
  #pragma unroll
  for (int s = 0; s < 5; s++) {
    const int lp = l + 2 - s;
    if (lp >= 0 && lp < Lc)
      acc += ldf(w + d * 5 + s) * HG[((rowb + lp) << 10) + d];
  }
  const float rs = rsqrtf(1.0f + 1e-5f);
  const float t = acc * rs * ldf(gn + d) + ldf(bb + d);
  OUT[gid] = f2b(t * fminf(fmaxf(t + 3.0f, 0.0f), 6.0f) * (1.0f / 6.0f));
}

// =====================================================================
extern "C" void kernel_launch(void* const* d_in, const int* in_sizes, int n_in,
                              void* d_out, int out_size, void* d_ws, size_t ws_size,
                              hipStream_t stream) {
  (void)in_sizes; (void)n_in; (void)out_size; (void)ws_size;
  const float* mem    = (const float*)d_in[0];
  const float* wq     = (const float*)d_in[1];
  const float* bq     = (const float*)d_in[2];
  const float* wk     = (const float*)d_in[3];
  const float* bk     = (const float*)d_in[4];
  const float* wv     = (const float*)d_in[5];
  const float* bv     = (const float*)d_in[6];
  const float* wo     = (const float*)d_in[7];
  const float* bo     = (const float*)d_in[8];
  const float* n1g    = (const float*)d_in[9];
  const float* n1b    = (const float*)d_in[10];
  const float* clng   = (const float*)d_in[11];
  const float* clnb   = (const float*)d_in[12];
  const float* pw1w   = (const float*)d_in[13];
  const float* pw1b   = (const float*)d_in[14];
  const float* dww    = (const float*)d_in[15];
  const float* dwb    = (const float*)d_in[16];
  const float* bng    = (const float*)d_in[17];
  const float* bnb    = (const float*)d_in[18];
  const float* pw2w   = (const float*)d_in[19];
  const float* pw2b   = (const float*)d_in[20];
  const float* projw  = (const float*)d_in[21];
  const float* projb  = (const float*)d_in[22];
  const float* proj2w = (const float*)d_in[23];
  const float* proj2b = (const float*)d_in[24];
  const float* lin1w  = (const float*)d_in[25];
  const float* lin1b  = (const float*)d_in[26];
  const float* lin2w  = (const float*)d_in[27];
  const float* lin2b  = (const float*)d_in[28];
  const float* n3g    = (const float*)d_in[29];
  const float* n3b    = (const float*)d_in[30];
  float* out = (float*)d_out;

  char* base = (char*)d_ws;
  float* qb   = (float*)base;          // q fp32 -> tgt2 fp32
  float* kb   = qb + TD;               // k fp32 -> mem1
  float* big1 = kb + TD;               // h1 lo -> mem2
  float* big2 = big1 + TD;             // h1 hi -> conv_out
  float* ob   = big2 + TD;             // V fp32 -> hg -> ffout
  unsigned short* abf  = (unsigned short*)(base + 5 * TD * 4);  // bf16 activation hub
  unsigned short* qbf  = abf + TD;
  unsigned short* kbf  = qbf + TD;
  unsigned short* vtb  = kbf + TD;     // V^T bf16  [b][1024 d][2048 l]
  unsigned short* m1T  = vtb + TD;
  unsigned short* ffbbf= m1T + TD;     // NT*FF = 4*TD shorts
  unsigned short* wt   = ffbbf + 4 * TD;
  unsigned short* wqT    = wt;            // [1024][1024]
  unsigned short* wkT    = wqT + MEG;
  unsigned short* wvT    = wkT + MEG;
  unsigned short* woT    = wvT + MEG;
  unsigned short* pw1T   = woT + MEG;     // [2048][1024]
  unsigned short* pw2T   = pw1T + 2*MEG;  // [1024][1024]
  unsigned short* proj2T = pw2T + MEG;    // [1024][1024]
  unsigned short* projwT = proj2T + MEG;  // [2048][2048]
  unsigned short* lin1T  = projwT + 4*MEG;// [4096][1024]
  unsigned short* lin2T  = lin1T + 4*MEG; // [1024][4096]
  float* pet = (float*)(lin2T + 4*MEG);   // [2048][64] rope table

  const dim3 blk(256);
  const long long LD = (long long)Lc * Dc;

  // ---- fused weight transposes (one launch) + rope table ----
  TPack tp;
  const float* tin[10]  = {wq, wk, wv, wo, pw1w, pw2w, proj2w, projw, lin1w, lin2w};
  unsigned short* tout[10] = {wqT, wkT, wvT, woT, pw1T, pw2T, proj2T, projwT, lin1T, lin2T};
  const int tR[10] = {1024,1024,1024,1024,1024,1024,1024,2048,1024,4096};
  const int tC[10] = {1024,1024,1024,1024,2048,1024,1024,2048,4096,1024};
  int startAcc = 0;
  for (int i = 0; i < 10; i++) {
    tp.in[i] = tin[i]; tp.out[i] = tout[i];
    tp.R[i] = tR[i]; tp.C[i] = tC[i]; tp.tx[i] = tC[i] / 64;
    tp.start[i] = startAcc;
    startAcc += (tR[i] / 64) * (tC[i] / 64);
  }
  fused_transpose_kernel<<<dim3(startAcc), blk, 0, stream>>>(tp);
  pe_fill_kernel<<<dim3(Lc * 64 / 256), blk, 0, stream>>>(pet);

  // ---- attention ----
  convert_bf16_kernel<<<dim3((unsigned)(TD/1024)),blk,0,stream>>>(mem, abf);
  mfma_gemm_kernel<EPI_BIAS,false><<<dim3(8,32,1),blk,0,stream>>>(abf,wqT,bq,nullptr,qb,nullptr,NT,Dc,Dc,0,0,0);
  mfma_gemm_kernel<EPI_BIAS,false><<<dim3(8,32,1),blk,0,stream>>>(abf,wkT,bk,nullptr,kb,nullptr,NT,Dc,Dc,0,0,0);
  mfma_gemm_kernel<EPI_BIAS,false><<<dim3(8,32,1),blk,0,stream>>>(abf,wvT,bv,nullptr,ob,nullptr,NT,Dc,Dc,0,0,0);
  rope2_kernel<<<dim3(2*NT*Hc/256),blk,0,stream>>>(qb, kb, pet, qbf, kbf);
  transpose_convert_kernel<<<dim3(16,32,2),blk,0,stream>>>(ob, vtb, 2048, 1024, LD, LD); // V^T per batch
  flash_attn_mfma_kernel<<<dim3(Lc/64, Bc*Hc),blk,0,stream>>>(qbf,kbf,vtb,abf);
  mfma_gemm_kernel<EPI_BIAS,false><<<dim3(8,32,1),blk,0,stream>>>(abf,woT,bo,nullptr,qb,nullptr,NT,Dc,Dc,0,0,0);
  ln_resadd_kernel<<<dim3(NT),blk,0,stream>>>(qb, mem, n1g, n1b, kb);   // mem1 -> kb

  // ---- conv block ----
  ln_plain_bf16_kernel<<<dim3(NT),blk,0,stream>>>(kb, clng, clnb, abf);
  mfma_gemm_kernel<EPI_BIAS,false><<<dim3(16,32,1),blk,0,stream>>>(abf,pw1T,pw1b,nullptr,big1,nullptr,NT,2*Dc,Dc,0,0,0);
  glu_kernel<<<dim3((unsigned)(TD/4/256)),blk,0,stream>>>(big1, ob);
  dwconv_bf16_kernel<<<dim3((unsigned)(TD/256)),blk,0,stream>>>(ob, dww, dwb, bng, bnb, abf);
  mfma_gemm_kernel<EPI_ADDROW0,false><<<dim3(8,32,1),blk,0,stream>>>(abf,pw2T,pw2b,kb,big2,nullptr,NT,Dc,Dc,0,0,0);

  // ---- proj path ----
  transpose_convert_kernel<<<dim3(16,32,2),blk,0,stream>>>(kb, m1T, 2048, 1024, LD, LD);
  mfma_gemm_kernel<EPI_BIAS_ROW,true><<<dim3(8,16,2),blk,0,stream>>>(projwT,m1T,projb,nullptr,nullptr,abf,Lc,Dc,Lc,0,LD,LD);
  mfma_gemm_kernel<EPI_ADD,false><<<dim3(8,32,1),blk,0,stream>>>(abf,proj2T,proj2b,big2,big1,nullptr,NT,Dc,Dc,0,0,0);

  // ---- feed-forward ----
  convert_bf16_kernel<<<dim3((unsigned)(TD/1024)),blk,0,stream>>>(big1, abf);
  mfma_gemm_kernel<EPI_GELU,true><<<dim3(32,32,1),blk,0,stream>>>(abf,lin1T,lin1b,nullptr,nullptr,ffbbf,NT,FFc,Dc,0,0,0);
  mfma_gemm_kernel<EPI_BIAS,false><<<dim3(8,32,1),blk,0,stream>>>(ffbbf,lin2T,lin2b,nullptr,ob,nullptr,NT,Dc,FFc,0,0,0);

  // ---- final: out = ln(mem2 + ffout) ----
  ln_sum_kernel<<<dim3(NT),blk,0,stream>>>(big1, ob, n3g, n3b, out);
}

// Round 7
// 783.079 us; speedup vs baseline: 14.0290x; 1.1347x over previous
//
#include <hip/hip_runtime.h>
#include <hip/hip_bf16.h>
#include <math.h>

constexpr int Bc = 2, Lc = 2048, Dc = 1024, Hc = 16, HDc = 64, FFc = 4096;
constexpr int NT = Bc * Lc;              // 4096 tokens
constexpr size_t TD = (size_t)NT * Dc;   // 4194304 elements per [B,L,D] tensor
constexpr size_t MEG = 1024 * 1024;

__device__ __forceinline__ float ldf(const float* p) { return *p; }
__device__ __forceinline__ unsigned short f2b(float f) {
  __hip_bfloat16 h = __float2bfloat16(f);
  return *reinterpret_cast<unsigned short*>(&h);
}

using frag   = __attribute__((ext_vector_type(8))) short;   // 8 bf16 (4 VGPRs)
using f32x4v = __attribute__((ext_vector_type(4))) float;   // MFMA C/D

// async global -> LDS, 16B per lane; LDS dest = wave-uniform base + lane*16
__device__ __forceinline__ void async16(const unsigned short* g, unsigned short* l) {
  __builtin_amdgcn_global_load_lds(
      (const __attribute__((address_space(1))) unsigned int*)g,
      (__attribute__((address_space(3))) unsigned int*)l, 16, 0, 0);
}

// ---------- block reductions (blockDim.x == 256 = 4 waves) ----------
__device__ __forceinline__ float block_sum(float v, float* red) {
  const int lane = threadIdx.x & 63, w = threadIdx.x >> 6;
  #pragma unroll
  for (int o = 32; o > 0; o >>= 1) v += __shfl_down(v, o, 64);
  __syncthreads();
  if (lane == 0) red[w] = v;
  __syncthreads();
  return red[0] + red[1] + red[2] + red[3];
}

// ---------- fp32 -> bf16 convert ----------
__global__ __launch_bounds__(256)
void convert_bf16_kernel(const float* __restrict__ IN, unsigned short* __restrict__ OUT)
{
  const size_t gid = (size_t)blockIdx.x * 256 + threadIdx.x;
  const float4 v = *(const float4*)(IN + gid * 4);
  ushort4 o;
  o.x = f2b(v.x); o.y = f2b(v.y); o.z = f2b(v.z); o.w = f2b(v.w);
  *(ushort4*)(OUT + gid * 4) = o;
}

// ---------- fp32 [R,C] -> bf16 [C,R] transpose-convert (z-batched) ----------
__global__ __launch_bounds__(256)
void transpose_convert_kernel(const float* __restrict__ IN, unsigned short* __restrict__ OUT,
                              int R, int C, long long sIn, long long sOut)
{
  __shared__ float tile[64][65];
  const int t = threadIdx.x;
  const float* in = IN + (long long)blockIdx.z * sIn;
  unsigned short* out = OUT + (long long)blockIdx.z * sOut;
  const int r0 = blockIdx.y * 64, c0 = blockIdx.x * 64;
  #pragma unroll
  for (int i = 0; i < 4; i++) {
    const int r = (t >> 4) + i * 16, c4 = (t & 15) * 4;
    const float4 v = *(const float4*)(in + (size_t)(r0 + r) * C + c0 + c4);
    tile[r][c4+0] = v.x; tile[r][c4+1] = v.y; tile[r][c4+2] = v.z; tile[r][c4+3] = v.w;
  }
  __syncthreads();
  #pragma unroll
  for (int i = 0; i < 4; i++) {
    const int cc = (t >> 4) + i * 16, rr4 = (t & 15) * 4;
    ushort4 o;
    o.x = f2b(tile[rr4+0][cc]); o.y = f2b(tile[rr4+1][cc]);
    o.z = f2b(tile[rr4+2][cc]); o.w = f2b(tile[rr4+3][cc]);
    *(ushort4*)(out + (size_t)(c0 + cc) * R + r0 + rr4) = o;
  }
}

// ---------- fused weight transposes: 10 segments in one launch ----------
struct TPack {
  const float* in[10]; unsigned short* out[10];
  int R[10], C[10], tx[10], start[10];
};
__global__ __launch_bounds__(256)
void fused_transpose_kernel(TPack p)
{
  __shared__ float tile[64][65];
  const int bid = blockIdx.x;
  int s = 0;
  #pragma unroll
  for (int i = 1; i < 10; i++) s = (bid >= p.start[i]) ? i : s;
  const float* in = p.in[s];
  unsigned short* out = p.out[s];
  const int R = p.R[s], C = p.C[s];
  const int local = bid - p.start[s];
  const int bx = local % p.tx[s], by = local / p.tx[s];
  const int r0 = by * 64, c0 = bx * 64;
  const int t = threadIdx.x;
  #pragma unroll
  for (int i = 0; i < 4; i++) {
    const int r = (t >> 4) + i * 16, c4 = (t & 15) * 4;
    const float4 v = *(const float4*)(in + (size_t)(r0 + r) * C + c0 + c4);
    tile[r][c4+0] = v.x; tile[r][c4+1] = v.y; tile[r][c4+2] = v.z; tile[r][c4+3] = v.w;
  }
  __syncthreads();
  #pragma unroll
  for (int i = 0; i < 4; i++) {
    const int cc = (t >> 4) + i * 16, rr4 = (t & 15) * 4;
    ushort4 o;
    o.x = f2b(tile[rr4+0][cc]); o.y = f2b(tile[rr4+1][cc]);
    o.z = f2b(tile[rr4+2][cc]); o.w = f2b(tile[rr4+3][cc]);
    *(ushort4*)(out + (size_t)(c0 + cc) * R + r0 + rr4) = o;
  }
}

// ---------- MFMA bf16 GEMM, global_load_lds staging ----------
// C[m,n] = sum_k A[m,k] * Bt[n,k]. 128x128 tile, BK=32.
// LDS [row][granule^(row&3)][8]; bank swizzle applied via the GLOBAL source index.
constexpr int EPI_BIAS = 0, EPI_BIAS_ROW = 1, EPI_GELU = 2, EPI_ADD = 3, EPI_ADDROW0 = 4;

template<int EPI, bool OUTBF, bool OUTBOTH>
__global__ __launch_bounds__(256)
void mfma_gemm_kernel(const unsigned short* __restrict__ A, const unsigned short* __restrict__ Bt,
                      const float* __restrict__ bias, const float* __restrict__ extra,
                      float* __restrict__ C, unsigned short* __restrict__ Cbf,
                      int M, int N, int K,
                      long long sA, long long sB, long long sC)
{
  __shared__ unsigned short As[128][4][8];
  __shared__ unsigned short Bs[128][4][8];
  const int tid = threadIdx.x;
  const int l = tid & 63, w = tid >> 6;
  const int wm = (w & 1) * 64, wn = (w >> 1) * 64;
  const int m0 = blockIdx.y * 128, n0 = blockIdx.x * 128;
  const unsigned short* Ap = A + (long long)blockIdx.z * sA;
  const unsigned short* Bp = Bt + (long long)blockIdx.z * sB;

  f32x4v acc[4][4];
  #pragma unroll
  for (int mt = 0; mt < 4; mt++)
    #pragma unroll
    for (int nt = 0; nt < 4; nt++) acc[mt][nt] = {0.f, 0.f, 0.f, 0.f};

  const int c_ = l >> 4, rm = l & 15;
  int rr[2], gg[2];
  #pragma unroll
  for (int j = 0; j < 2; j++) {
    const int chunk = w * 128 + j * 64 + l;
    rr[j] = chunk >> 2;
    gg[j] = (chunk & 3) ^ (rr[j] & 3);
  }

  for (int k0 = 0; k0 < K; k0 += 32) {
    __syncthreads();
    #pragma unroll
    for (int j = 0; j < 2; j++) {
      async16(Ap + (size_t)(m0 + rr[j]) * K + k0 + gg[j] * 8,
              &As[0][0][0] + (size_t)(w * 128 + j * 64) * 8);
      async16(Bp + (size_t)(n0 + rr[j]) * K + k0 + gg[j] * 8,
              &Bs[0][0][0] + (size_t)(w * 128 + j * 64) * 8);
    }
    __syncthreads();   // drains vmcnt before barrier

    frag af[4], bfr[4];
    #pragma unroll
    for (int mt = 0; mt < 4; mt++)
      af[mt] = *(const frag*)&As[wm + mt * 16 + rm][c_ ^ (rm & 3)][0];
    #pragma unroll
    for (int nt = 0; nt < 4; nt++)
      bfr[nt] = *(const frag*)&Bs[wn + nt * 16 + rm][c_ ^ (rm & 3)][0];
    #pragma unroll
    for (int mt = 0; mt < 4; mt++)
      #pragma unroll
      for (int nt = 0; nt < 4; nt++)
        acc[mt][nt] = __builtin_amdgcn_mfma_f32_16x16x32_bf16(af[mt], bfr[nt], acc[mt][nt], 0, 0, 0);
  }

  float* Cp = C + (long long)blockIdx.z * sC;
  unsigned short* Cbp = Cbf + (long long)blockIdx.z * sC;
  #pragma unroll
  for (int mt = 0; mt < 4; mt++) {
    #pragma unroll
    for (int nt = 0; nt < 4; nt++) {
      #pragma unroll
      for (int i = 0; i < 4; i++) {
        const int m = m0 + wm + mt * 16 + c_ * 4 + i;   // C/D: row=(lane>>4)*4+reg
        const int n = n0 + wn + nt * 16 + rm;           //      col=lane&15
        float r = acc[mt][nt][i];
        if constexpr (EPI == EPI_BIAS || EPI == EPI_GELU || EPI == EPI_ADD || EPI == EPI_ADDROW0)
          r += ldf(bias + n);
        if constexpr (EPI == EPI_BIAS_ROW) r += ldf(bias + m);
        if constexpr (EPI == EPI_GELU)
          r = 0.5f * r * (1.0f + erff(r * 0.70710678118654752f));
        if constexpr (EPI == EPI_ADD) r += extra[(size_t)m * N + n];
        if constexpr (EPI == EPI_ADDROW0) r += extra[(size_t)(m >> 11) * ((size_t)Lc * Dc) + n];
        if constexpr (OUTBOTH) { Cp[(size_t)m * N + n] = r; Cbp[(size_t)m * N + n] = f2b(r); }
        else if constexpr (OUTBF) Cbp[(size_t)m * N + n] = f2b(r);
        else                      Cp[(size_t)m * N + n] = r;
      }
    }
  }
}

// ---------- RoPE table fill ----------
__global__ __launch_bounds__(256)
void pe_fill_kernel(float* __restrict__ pet)
{
  const int gid = blockIdx.x * 256 + threadIdx.x;  // Lc*64
  const int l = gid >> 6, t = gid & 63;
  const int j = t & 31;
  const float wj = exp2f(-(float)j * (13.2877123795494f / 32.0f));
  const float ang = (float)l * wj;
  pet[gid] = (t < 32) ? cosf(ang) : sinf(ang);
}

// ---------- fused RoPE for Q and K: fp32 in, bf16 out ----------
__global__ __launch_bounds__(256)
void rope2_kernel(const float* __restrict__ Qi, const float* __restrict__ Ki,
                  const float* __restrict__ pet,
                  unsigned short* __restrict__ Qo, unsigned short* __restrict__ Ko)
{
  int gid = blockIdx.x * 256 + threadIdx.x;  // 2*NT*Hc
  const int sel = gid >= NT * Hc;
  if (sel) gid -= NT * Hc;
  const float* X = sel ? Ki : Qi;
  unsigned short* O = sel ? Ko : Qo;
  const int h = gid & (Hc - 1);
  const int token = gid >> 4;
  const int l = token & (Lc - 1);
  const float* p = X + (size_t)token * Dc + h * HDc;
  unsigned short* po = O + (size_t)token * Dc + h * HDc;
  const float* pr = pet + l * 64;
  float x[64], out[64];
  #pragma unroll
  for (int i = 0; i < 16; i++) *(float4*)&x[4*i] = *(const float4*)&p[4*i];
  #pragma unroll
  for (int u = 0; u < 32; u++) {
    const int base = (u < 16) ? (2 * u) : (32 + 2 * (u - 16));
    const float c = pr[base], s = pr[base + 1];
    out[u]      = x[2*u] * c - x[2*u+1] * s;
    out[32 + u] = x[2*u] * s + x[2*u+1] * c;
  }
  #pragma unroll
  for (int i = 0; i < 16; i++) {
    ushort4 o;
    o.x = f2b(out[4*i+0]); o.y = f2b(out[4*i+1]);
    o.z = f2b(out[4*i+2]); o.w = f2b(out[4*i+3]);
    *(ushort4*)&po[4*i] = o;
  }
}

// ---------- MFMA flash attention v3 ----------
// One block = 128 q-rows x one (b,h). 4 waves x 32 q-rows.
// S^T = K*Q^T (rows=k, cols=q): softmax row at fixed lane (2-shfl reduce),
// P exits with 4 consecutive k per reg quad -> packed ushort4 stores into Ps.
// PV: O = P*V^T with P natural A-layout, Vt natural [d][k] B-layout.
// All staging via global_load_lds; bank swizzle on the global source index.
__global__ __launch_bounds__(256)
void flash_attn_mfma_kernel(const unsigned short* __restrict__ Q,
                            const unsigned short* __restrict__ K,
                            const unsigned short* __restrict__ VT,
                            unsigned short* __restrict__ O)
{
  __shared__ unsigned short Qs[128][8][8];
  __shared__ unsigned short Ks[64][8][8];
  __shared__ unsigned short Vt[64][8][8];
  __shared__ unsigned short Ps[128][72];
  const int tid = threadIdx.x;
  const int l = tid & 63, w = tid >> 6;
  const int lg = l >> 4, lm = l & 15;
  const int q0 = blockIdx.x * 128;
  const int bh = blockIdx.y;
  const int b = bh >> 4, h = bh & 15;
  const size_t rowbase = (size_t)b * Lc;
  const size_t vbase = (size_t)b * Lc * Dc;
  const int dbase = h * 64;
  const float sc1 = 0.125f * 1.44269504f;                  // scale * log2(e)
  const float sl2 = exp2f(-0.5f * (float)h) * 1.44269504f; // slope * log2(e)

  // ---- stage Q (128 rows x 64 d = 1024 chunks) ----
  #pragma unroll
  for (int j = 0; j < 4; j++) {
    const int chunk = (w * 4 + j) * 64 + l;
    const int r = chunk >> 3, gsrc = (chunk & 7) ^ (r & 7);
    async16(Q + (rowbase + q0 + r) * Dc + dbase + gsrc * 8,
            &Qs[0][0][0] + (size_t)chunk * 8);
  }
  __syncthreads();
  frag qf[2][2];
  #pragma unroll
  for (int qt = 0; qt < 2; qt++)
    #pragma unroll
    for (int s = 0; s < 2; s++)
      qf[qt][s] = *(const frag*)&Qs[w * 32 + qt * 16 + lm][(s * 4 + lg) ^ (lm & 7)][0];

  float m_i[2], l_i[2];
  f32x4v acc_o[2][4];
  #pragma unroll
  for (int qt = 0; qt < 2; qt++) {
    m_i[qt] = -3.0e38f; l_i[qt] = 0.f;
    #pragma unroll
    for (int dt = 0; dt < 4; dt++) acc_o[qt][dt] = {0.f, 0.f, 0.f, 0.f};
  }

  for (int k0 = 0; k0 < Lc; k0 += 64) {
    __syncthreads();   // prior tile reads complete
    #pragma unroll
    for (int j = 0; j < 2; j++) {
      const int chunk = (w * 2 + j) * 64 + l;
      const int r = chunk >> 3, gsrc = (chunk & 7) ^ (r & 7);
      async16(K + (rowbase + k0 + r) * Dc + dbase + gsrc * 8,
              &Ks[0][0][0] + (size_t)chunk * 8);
      async16(VT + vbase + (size_t)(dbase + r) * Lc + k0 + gsrc * 8,
              &Vt[0][0][0] + (size_t)chunk * 8);
    }
    __syncthreads();

    // ---- S^T = K Q^T : rows k (64), cols q (32 of this wave) ----
    f32x4v st[2][4];
    #pragma unroll
    for (int qt = 0; qt < 2; qt++)
      #pragma unroll
      for (int kt = 0; kt < 4; kt++) st[qt][kt] = {0.f, 0.f, 0.f, 0.f};
    #pragma unroll
    for (int kt = 0; kt < 4; kt++) {
      #pragma unroll
      for (int s = 0; s < 2; s++) {
        frag kf = *(const frag*)&Ks[kt * 16 + lm][(s * 4 + lg) ^ (lm & 7)][0];
        #pragma unroll
        for (int qt = 0; qt < 2; qt++)
          st[qt][kt] = __builtin_amdgcn_mfma_f32_16x16x32_bf16(kf, qf[qt][s], st[qt][kt], 0, 0, 0);
      }
    }

    // ---- softmax (base-2); lane's q = qt*16+lm; k = kt*16 + lg*4 + i ----
    #pragma unroll
    for (int qt = 0; qt < 2; qt++) {
      const float qg = (float)(q0 + w * 32 + qt * 16 + lm);
      float sv[4][4], tmax = -3.0e38f;
      #pragma unroll
      for (int kt = 0; kt < 4; kt++)
        #pragma unroll
        for (int i = 0; i < 4; i++) {
          const float kg = (float)(k0 + kt * 16 + lg * 4 + i);
          const float v = st[qt][kt][i] * sc1 + sl2 * fmaxf(qg - kg, 0.0f);
          sv[kt][i] = v; tmax = fmaxf(tmax, v);
        }
      tmax = fmaxf(tmax, __shfl_xor(tmax, 16, 64));
      tmax = fmaxf(tmax, __shfl_xor(tmax, 32, 64));
      const float mnew = fmaxf(m_i[qt], tmax);
      const float alpha = exp2f(m_i[qt] - mnew);
      m_i[qt] = mnew;
      float rsum = 0.f;
      const int qrow = w * 32 + qt * 16 + lm;
      #pragma unroll
      for (int kt = 0; kt < 4; kt++) {
        const float p0 = exp2f(sv[kt][0] - mnew), p1 = exp2f(sv[kt][1] - mnew);
        const float p2 = exp2f(sv[kt][2] - mnew), p3 = exp2f(sv[kt][3] - mnew);
        rsum += (p0 + p1) + (p2 + p3);
        ushort4 pk4;
        pk4.x = f2b(p0); pk4.y = f2b(p1); pk4.z = f2b(p2); pk4.w = f2b(p3);
        *(ushort4*)&Ps[qrow][kt * 16 + lg * 4] = pk4;   // 4 consecutive k
      }
      rsum += __shfl_xor(rsum, 16, 64);
      rsum += __shfl_xor(rsum, 32, 64);
      l_i[qt] = l_i[qt] * alpha + rsum;
      float aO[4];
      #pragma unroll
      for (int i = 0; i < 4; i++) aO[i] = __shfl(alpha, lg * 4 + i, 64);
      #pragma unroll
      for (int dt = 0; dt < 4; dt++)
        #pragma unroll
        for (int i = 0; i < 4; i++) acc_o[qt][dt][i] *= aO[i];
    }

    // ---- O += P V (Ps rows wave-private; same-wave DS order suffices) ----
    #pragma unroll
    for (int c = 0; c < 2; c++) {
      frag ap[2];
      #pragma unroll
      for (int qt = 0; qt < 2; qt++)
        ap[qt] = *(const frag*)&Ps[w * 32 + qt * 16 + lm][c * 32 + lg * 8];
      #pragma unroll
      for (int dt = 0; dt < 4; dt++) {
        frag bv = *(const frag*)&Vt[dt * 16 + lm][(c * 4 + lg) ^ (lm & 7)][0];
        #pragma unroll
        for (int qt = 0; qt < 2; qt++)
          acc_o[qt][dt] = __builtin_amdgcn_mfma_f32_16x16x32_bf16(ap[qt], bv, acc_o[qt][dt], 0, 0, 0);
      }
    }
  }

  // ---- epilogue: normalize, bounce through Ps, coalesced store ----
  #pragma unroll
  for (int qt = 0; qt < 2; qt++) {
    float lO[4];
    #pragma unroll
    for (int i = 0; i < 4; i++) lO[i] = 1.0f / __shfl(l_i[qt], lg * 4 + i, 64);
    #pragma unroll
    for (int dt = 0; dt < 4; dt++)
      #pragma unroll
      for (int i = 0; i < 4; i++)
        Ps[w * 32 + qt * 16 + lg * 4 + i][dt * 16 + lm] = f2b(acc_o[qt][dt][i] * lO[i]);
  }
  __syncthreads();
  #pragma unroll
  for (int j = 0; j < 4; j++) {
    const int chunk = (w * 4 + j) * 64 + l;
    const int r = chunk >> 3, g = chunk & 7;
    alignas(16) unsigned short tmp[8];
    #pragma unroll
    for (int t = 0; t < 8; t++) tmp[t] = Ps[r][g * 8 + t];
    *(uint4*)(O + (rowbase + q0 + r) * Dc + dbase + g * 8) = *(uint4*)tmp;
  }
}

// ---------- fused: mem1 = RES + ln(X;n1) -> fp32; hln = ln(mem1;cln) -> bf16 ----
__global__ __launch_bounds__(256)
void ln_res_cln_kernel(const float* __restrict__ X, const float* __restrict__ RES,
                       const float* __restrict__ g1, const float* __restrict__ b1,
                       const float* __restrict__ g2, const float* __restrict__ b2,
                       float* __restrict__ OUT1, unsigned short* __restrict__ OUT2)
{
  __shared__ float red4[4];
  const int row = blockIdx.x, tid = threadIdx.x;
  const size_t base = (size_t)row * Dc + tid * 4;
  const float4 xv = *(const float4*)(X + base);
  float s = xv.x + xv.y + xv.z + xv.w;
  s = block_sum(s, red4);
  const float mean = s * (1.0f / Dc);
  const float d0 = xv.x-mean, d1 = xv.y-mean, d2 = xv.z-mean, d3 = xv.w-mean;
  float ss = d0*d0 + d1*d1 + d2*d2 + d3*d3;
  ss = block_sum(ss, red4);
  const float rstd = rsqrtf(ss * (1.0f / Dc) + 1e-5f);
  const int c = tid * 4;
  const float4 rv = *(const float4*)(RES + base);
  float y0 = rv.x + d0*rstd*ldf(g1+c+0) + ldf(b1+c+0);
  float y1 = rv.y + d1*rstd*ldf(g1+c+1) + ldf(b1+c+1);
  float y2 = rv.z + d2*rstd*ldf(g1+c+2) + ldf(b1+c+2);
  float y3 = rv.w + d3*rstd*ldf(g1+c+3) + ldf(b1+c+3);
  *(float4*)(OUT1 + base) = make_float4(y0, y1, y2, y3);
  float s2 = y0 + y1 + y2 + y3;
  s2 = block_sum(s2, red4);
  const float mean2 = s2 * (1.0f / Dc);
  const float e0 = y0-mean2, e1 = y1-mean2, e2 = y2-mean2, e3 = y3-mean2;
  float ss2 = e0*e0 + e1*e1 + e2*e2 + e3*e3;
  ss2 = block_sum(ss2, red4);
  const float rstd2 = rsqrtf(ss2 * (1.0f / Dc) + 1e-5f);
  ushort4 o;
  o.x = f2b(e0*rstd2*ldf(g2+c+0) + ldf(b2+c+0));
  o.y = f2b(e1*rstd2*ldf(g2+c+1) + ldf(b2+c+1));
  o.z = f2b(e2*rstd2*ldf(g2+c+2) + ldf(b2+c+2));
  o.w = f2b(e3*rstd2*ldf(g2+c+3) + ldf(b2+c+3));
  *(ushort4*)(OUT2 + base) = o;
}

__global__ __launch_bounds__(256)   // OUT = ln(X + Y)
void ln_sum_kernel(const float* __restrict__ X, const float* __restrict__ Y,
                   const float* __restrict__ g, const float* __restrict__ be,
                   float* __restrict__ OUT)
{
  __shared__ float red4[4];
  const int row = blockIdx.x, tid = threadIdx.x;
  const size_t base = (size_t)row * Dc + tid * 4;
  const float4 xv = *(const float4*)(X + base);
  const float4 yv = *(const float4*)(Y + base);
  const float x0 = xv.x+yv.x, x1 = xv.y+yv.y, x2 = xv.z+yv.z, x3 = xv.w+yv.w;
  float s = x0 + x1 + x2 + x3;
  s = block_sum(s, red4);
  const float mean = s * (1.0f / Dc);
  const float d0 = x0-mean, d1 = x1-mean, d2 = x2-mean, d3 = x3-mean;
  float ss = d0*d0 + d1*d1 + d2*d2 + d3*d3;
  ss = block_sum(ss, red4);
  const float rstd = rsqrtf(ss * (1.0f / Dc) + 1e-5f);
  const int c = tid * 4;
  float4 o;
  o.x = d0*rstd*ldf(g+c+0) + ldf(be+c+0);
  o.y = d1*rstd*ldf(g+c+1) + ldf(be+c+1);
  o.z = d2*rstd*ldf(g+c+2) + ldf(be+c+2);
  o.w = d3*rstd*ldf(g+c+3) + ldf(be+c+3);
  *(float4*)(OUT + base) = o;
}

// ---------- GLU ----------
__global__ __launch_bounds__(256)
void glu_kernel(const float* __restrict__ H1, float* __restrict__ HG)
{
  const int gid = blockIdx.x * 256 + threadIdx.x;
  const int t = gid >> 8;
  const int c4 = (gid & 255) * 4;
  const float* p = H1 + (size_t)t * (2 * Dc);
  const float4 a = *(const float4*)(p + c4);
  const float4 gg = *(const float4*)(p + Dc + c4);
  float4 o;
  o.x = a.x / (1.0f + expf(-gg.x));
  o.y = a.y / (1.0f + expf(-gg.y));
  o.z = a.z / (1.0f + expf(-gg.z));
  o.w = a.w / (1.0f + expf(-gg.w));
  *(float4*)(HG + (size_t)t * Dc + c4) = o;
}

// ---------- depthwise conv K=5 (+bias, bn-scale, hardswish), bf16 out ----------
__global__ __launch_bounds__(256)
void dwconv_bf16_kernel(const float* __restrict__ HG, const float* __restrict__ w,
                        const float* __restrict__ wb, const float* __restrict__ gn,
                        const float* __restrict__ bb, unsigned short* __restrict__ OUT)
{
  const int gid = blockIdx.x * 256 + threadIdx.x;
  const int d = gid & (Dc - 1);
  const int l = (gid >> 10) & (Lc - 1);
  const int b = gid >> 21;
  const size_t rowb = (size_t)b * Lc;
  float acc = ldf(wb + d);
  #pragma unroll
  for (int s = 0; s < 5; s++) {
    const int lp = l + 2 - s;
    if (lp >= 0 && lp < Lc)
      acc += ldf(w + d * 5 + s) * HG[((rowb + lp) << 10) + d];
  }
  const float rs = rsqrtf(1.0f + 1e-5f);
  const float t = acc * rs * ldf(gn + d) + ldf(bb + d);
  OUT[gid] = f2b(t * fminf(fmaxf(t + 3.0f, 0.0f), 6.0f) * (1.0f / 6.0f));
}

// =====================================================================
extern "C" void kernel_launch(void* const* d_in, const int* in_sizes, int n_in,
                              void* d_out, int out_size, void* d_ws, size_t ws_size,
                              hipStream_t stream) {
  (void)in_sizes; (void)n_in; (void)out_size; (void)ws_size;
  const float* mem    = (const float*)d_in[0];
  const float* wq     = (const float*)d_in[1];
  const float* bq     = (const float*)d_in[2];
  const float* wk     = (const float*)d_in[3];
  const float* bk     = (const float*)d_in[4];
  const float* wv     = (const float*)d_in[5];
  const float* bv     = (const float*)d_in[6];
  const float* wo     = (const float*)d_in[7];
  const float* bo     = (const float*)d_in[8];
  const float* n1g    = (const float*)d_in[9];
  const float* n1b    = (const float*)d_in[10];
  const float* clng   = (const float*)d_in[11];
  const float* clnb   = (const float*)d_in[12];
  const float* pw1w   = (const float*)d_in[13];
  const float* pw1b   = (const float*)d_in[14];
  const float* dww    = (const float*)d_in[15];
  const float* dwb    = (const float*)d_in[16];
  const float* bng    = (const float*)d_in[17];
  const float* bnb    = (const float*)d_in[18];
  const float* pw2w   = (const float*)d_in[19];
  const float* pw2b   = (const float*)d_in[20];
  const float* projw  = (const float*)d_in[21];
  const float* projb  = (const float*)d_in[22];
  const float* proj2w = (const float*)d_in[23];
  const float* proj2b = (const float*)d_in[24];
  const float* lin1w  = (const float*)d_in[25];
  const float* lin1b  = (const float*)d_in[26];
  const float* lin2w  = (const float*)d_in[27];
  const float* lin2b  = (const float*)d_in[28];
  const float* n3g    = (const float*)d_in[29];
  const float* n3b    = (const float*)d_in[30];
  float* out = (float*)d_out;

  char* base = (char*)d_ws;
  float* qb   = (float*)base;          // q fp32 -> tgt2 fp32
  float* kb   = qb + TD;               // k fp32 -> mem1
  float* big1 = kb + TD;               // h1 lo -> mem2 fp32
  float* big2 = big1 + TD;             // h1 hi -> conv_out
  float* ob   = big2 + TD;             // V fp32 -> hg -> ffout
  unsigned short* abf  = (unsigned short*)(base + 5 * TD * 4);  // bf16 hub
  unsigned short* qbf  = abf + TD;     // rope-q -> mem2 bf16
  unsigned short* kbf  = qbf + TD;
  unsigned short* vtb  = kbf + TD;     // V^T bf16  [b][1024 d][2048 l]
  unsigned short* m1T  = vtb + TD;
  unsigned short* ffbbf= m1T + TD;     // NT*FF = 4*TD shorts
  unsigned short* wt   = ffbbf + 4 * TD;
  unsigned short* wqT    = wt;            // [1024][1024]
  unsigned short* wkT    = wqT + MEG;
  unsigned short* wvT    = wkT + MEG;
  unsigned short* woT    = wvT + MEG;
  unsigned short* pw1T   = woT + MEG;     // [2048][1024]
  unsigned short* pw2T   = pw1T + 2*MEG;  // [1024][1024]
  unsigned short* proj2T = pw2T + MEG;    // [1024][1024]
  unsigned short* projwT = proj2T + MEG;  // [2048][2048]
  unsigned short* lin1T  = projwT + 4*MEG;// [4096][1024]
  unsigned short* lin2T  = lin1T + 4*MEG; // [1024][4096]
  float* pet = (float*)(lin2T + 4*MEG);   // [2048][64] rope table

  const dim3 blk(256);
  const long long LD = (long long)Lc * Dc;

  // ---- fused weight transposes + rope table ----
  TPack tp;
  const float* tin[10]  = {wq, wk, wv, wo, pw1w, pw2w, proj2w, projw, lin1w, lin2w};
  unsigned short* tout[10] = {wqT, wkT, wvT, woT, pw1T, pw2T, proj2T, projwT, lin1T, lin2T};
  const int tR[10] = {1024,1024,1024,1024,1024,1024,1024,2048,1024,4096};
  const int tC[10] = {1024,1024,1024,1024,2048,1024,1024,2048,4096,1024};
  int startAcc = 0;
  for (int i = 0; i < 10; i++) {
    tp.in[i] = tin[i]; tp.out[i] = tout[i];
    tp.R[i] = tR[i]; tp.C[i] = tC[i]; tp.tx[i] = tC[i] / 64;
    tp.start[i] = startAcc;
    startAcc += (tR[i] / 64) * (tC[i] / 64);
  }
  fused_transpose_kernel<<<dim3(startAcc), blk, 0, stream>>>(tp);
  pe_fill_kernel<<<dim3(Lc * 64 / 256), blk, 0, stream>>>(pet);

  // ---- attention ----
  convert_bf16_kernel<<<dim3((unsigned)(TD/1024)),blk,0,stream>>>(mem, abf);
  mfma_gemm_kernel<EPI_BIAS,false,false><<<dim3(8,32,1),blk,0,stream>>>(abf,wqT,bq,nullptr,qb,nullptr,NT,Dc,Dc,0,0,0);
  mfma_gemm_kernel<EPI_BIAS,false,false><<<dim3(8,32,1),blk,0,stream>>>(abf,wkT,bk,nullptr,kb,nullptr,NT,Dc,Dc,0,0,0);
  mfma_gemm_kernel<EPI_BIAS,false,false><<<dim3(8,32,1),blk,0,stream>>>(abf,wvT,bv,nullptr,ob,nullptr,NT,Dc,Dc,0,0,0);
  rope2_kernel<<<dim3(2*NT*Hc/256),blk,0,stream>>>(qb, kb, pet, qbf, kbf);
  transpose_convert_kernel<<<dim3(16,32,2),blk,0,stream>>>(ob, vtb, 2048, 1024, LD, LD); // V^T per batch
  flash_attn_mfma_kernel<<<dim3(Lc/128, Bc*Hc),blk,0,stream>>>(qbf,kbf,vtb,abf);
  mfma_gemm_kernel<EPI_BIAS,false,false><<<dim3(8,32,1),blk,0,stream>>>(abf,woT,bo,nullptr,qb,nullptr,NT,Dc,Dc,0,0,0);
  // mem1 (fp32 -> kb) and ln(mem1) (bf16 -> abf) in one pass
  ln_res_cln_kernel<<<dim3(NT),blk,0,stream>>>(qb, mem, n1g, n1b, clng, clnb, kb, abf);

  // ---- conv block ----
  mfma_gemm_kernel<EPI_BIAS,false,false><<<dim3(16,32,1),blk,0,stream>>>(abf,pw1T,pw1b,nullptr,big1,nullptr,NT,2*Dc,Dc,0,0,0);
  glu_kernel<<<dim3((unsigned)(TD/4/256)),blk,0,stream>>>(big1, ob);
  dwconv_bf16_kernel<<<dim3((unsigned)(TD/256)),blk,0,stream>>>(ob, dww, dwb, bng, bnb, abf);
  mfma_gemm_kernel<EPI_ADDROW0,false,false><<<dim3(8,32,1),blk,0,stream>>>(abf,pw2T,pw2b,kb,big2,nullptr,NT,Dc,Dc,0,0,0);

  // ---- proj path ----
  transpose_convert_kernel<<<dim3(16,32,2),blk,0,stream>>>(kb, m1T, 2048, 1024, LD, LD);
  mfma_gemm_kernel<EPI_BIAS_ROW,true,false><<<dim3(8,16,2),blk,0,stream>>>(projwT,m1T,projb,nullptr,nullptr,abf,Lc,Dc,Lc,0,LD,LD);
  // mem2 = proj@proj2 + conv_out: fp32 -> big1 AND bf16 -> qbf (feeds lin1)
  mfma_gemm_kernel<EPI_ADD,false,true><<<dim3(8,32,1),blk,0,stream>>>(abf,proj2T,proj2b,big2,big1,qbf,NT,Dc,Dc,0,0,0);

  // ---- feed-forward ----
  mfma_gemm_kernel<EPI_GELU,true,false><<<dim3(32,32,1),blk,0,stream>>>(qbf,lin1T,lin1b,nullptr,nullptr,ffbbf,NT,FFc,Dc,0,0,0);
  mfma_gemm_kernel<EPI_BIAS,false,false><<<dim3(8,32,1),blk,0,stream>>>(ffbbf,lin2T,lin2b,nullptr,ob,nullptr,NT,Dc,FFc,0,0,0);

  // ---- final: out = ln(mem2 + ffout) ----
  ln_sum_kernel<<<dim3(NT),blk,0,stream>>>(big1, ob, n3g, n3b, out);
}